// Round 2
// baseline (2366.941 us; speedup 1.0000x reference)
//
#include <hip/hip_runtime.h>
#include <cstdint>
#include <cstddef>

// ---------------- problem constants ----------------
#define BB 4
#define LL 4096
#define DD 768
#define KK 12
#define KQ 6
#define NRP 2
#define HH 64
#define KSZ 4
#define DIM_MEM 768
#define DIM_MEMT 780
#define DIM_Q 768
#define DIM_CONV 1548
#define DIM_SKIP 192
#define DIM_SWH 384
#define DIM_TOTAL 1752
#define FLATC 768
#define TTOK (BB*LL)          // 16384 tokens
#define NCHUNK 32
#define LCHUNK 128            // LL / NCHUNK

// ---------------- helpers ----------------
__device__ __forceinline__ float sigm(float x) { return 1.0f / (1.0f + expf(-x)); }
__device__ __forceinline__ float softplusf(float x) {
    return (x > 0.f) ? (x + log1pf(expf(-x))) : log1pf(expf(x));
}
__device__ __forceinline__ float blockReduceSum256(float v, float* sbuf) {
    #pragma unroll
    for (int off = 32; off > 0; off >>= 1) v += __shfl_xor(v, off);
    const int wid = threadIdx.x >> 6;
    __syncthreads();
    if ((threadIdx.x & 63) == 0) sbuf[wid] = v;
    __syncthreads();
    float tot = sbuf[0] + sbuf[1] + sbuf[2] + sbuf[3];
    return tot;
}

// ---------------- generic fp32 GEMM: C[M,N] = A[M,Kd] @ B[Kd,N] ----------------
// M % 128 == 0, Kd % 8 == 0; N guarded (must be % 4 == 0).
__launch_bounds__(256)
__global__ void sgemm128(const float* __restrict__ A, const float* __restrict__ B,
                         float* __restrict__ C, int Mdim, int Ndim, int Kd) {
    __shared__ float As[8][128];
    __shared__ float Bs[8][128];
    const int tid = threadIdx.x;
    const int bm = blockIdx.x * 128;
    const int bn = blockIdx.y * 128;
    const int tx = tid & 15, ty = tid >> 4;
    const int aRow = tid >> 1, aCol = (tid & 1) * 4;
    const int bRow = tid >> 5, bCol = (tid & 31) * 4;
    float acc[8][8] = {};
    for (int k0 = 0; k0 < Kd; k0 += 8) {
        const float4 av = *reinterpret_cast<const float4*>(&A[(size_t)(bm + aRow) * Kd + k0 + aCol]);
        As[aCol + 0][aRow] = av.x; As[aCol + 1][aRow] = av.y;
        As[aCol + 2][aRow] = av.z; As[aCol + 3][aRow] = av.w;
        float4 bv = make_float4(0.f, 0.f, 0.f, 0.f);
        if (bn + bCol < Ndim)
            bv = *reinterpret_cast<const float4*>(&B[(size_t)(k0 + bRow) * Ndim + bn + bCol]);
        *reinterpret_cast<float4*>(&Bs[bRow][bCol]) = bv;
        __syncthreads();
        #pragma unroll
        for (int kk = 0; kk < 8; ++kk) {
            float af[8], bf[8];
            *(float4*)&af[0] = *(float4*)&As[kk][ty * 8];
            *(float4*)&af[4] = *(float4*)&As[kk][ty * 8 + 4];
            *(float4*)&bf[0] = *(float4*)&Bs[kk][tx * 8];
            *(float4*)&bf[4] = *(float4*)&Bs[kk][tx * 8 + 4];
            #pragma unroll
            for (int i = 0; i < 8; ++i)
                #pragma unroll
                for (int j = 0; j < 8; ++j)
                    acc[i][j] = fmaf(af[i], bf[j], acc[i][j]);
        }
        __syncthreads();
    }
    #pragma unroll
    for (int i = 0; i < 8; ++i) {
        const int row = bm + ty * 8 + i;
        #pragma unroll
        for (int j4 = 0; j4 < 8; j4 += 4) {
            const int col = bn + tx * 8 + j4;
            if (col < Ndim) {
                float4 cv = make_float4(acc[i][j4], acc[i][j4 + 1], acc[i][j4 + 2], acc[i][j4 + 3]);
                *reinterpret_cast<float4*>(&C[(size_t)row * Ndim + col]) = cv;
            }
        }
    }
}

// ---------------- feature kernel: conv+silu, rms(k), rms(q), dt/decay, phase trig ----------------
// one block (256 thr) per token; all pointers are PASS-LOCAL (tok in [0, TP))
__launch_bounds__(256)
__global__ void feat_kernel(const float* __restrict__ Z, const float* __restrict__ conv_w,
                            const float* __restrict__ wk, const float* __restrict__ wq,
                            const float* __restrict__ theta_raw, const float* __restrict__ dt_scale,
                            const float* __restrict__ dt_bias, const float* __restrict__ log_A,
                            const float* __restrict__ phase_scale,
                            float* __restrict__ stack, float* __restrict__ decay,
                            float* __restrict__ qbuf) {
    __shared__ float zc[DIM_CONV];
    __shared__ float red[8];
    const int tok = blockIdx.x;
    const int b = tok / LL, t = tok % LL;   // b is pass-local batch index
    const int tid = threadIdx.x;

    // causal depthwise conv (w[3]*x[t] + w[2]*x[t-1] + w[1]*x[t-2] + w[0]*x[t-3]) then SiLU
    for (int c = tid; c < DIM_CONV; c += 256) {
        float s = 0.f;
        #pragma unroll
        for (int j = 0; j < KSZ; ++j) {
            const int tt = t + j - (KSZ - 1);
            if (tt >= 0)
                s = fmaf(conv_w[j * DIM_CONV + c], Z[((size_t)(b * LL + tt)) * DIM_TOTAL + c], s);
        }
        zc[c] = s * sigm(s);   // silu
    }
    __syncthreads();

    // q = rms(q_raw over 768) * wq   (q_raw = zc[780..1548))
    float part = 0.f;
    #pragma unroll
    for (int it = 0; it < 3; ++it) {
        const float v = zc[DIM_MEMT + tid + it * 256];
        part = fmaf(v, v, part);
    }
    const float qss = blockReduceSum256(part, red);
    const float qrs = rsqrtf(qss / (float)DIM_Q + 1e-6f);
    #pragma unroll
    for (int it = 0; it < 3; ++it) {
        const int c = tid + it * 256;
        qbuf[(size_t)tok * DIM_Q + c] = zc[DIM_MEMT + c] * qrs * wq[c];
    }

    // per-k: rms over H, dt, decay, phase trig, write stack
    const int wave = tid >> 6, lane = tid & 63;
    for (int k = wave; k < KK; k += 4) {
        const float v = zc[k * HH + lane];
        float ss = v * v;
        #pragma unroll
        for (int off = 32; off > 0; off >>= 1) ss += __shfl_xor(ss, off);
        const float rs = rsqrtf(ss / (float)HH + 1e-6f);
        const float kval = v * rs * wk[lane];

        const float sraw = zc[DIM_MEM + k];
        float lin = fmaf(dt_scale[k], sraw, dt_bias[k]);
        lin = fminf(fmaxf(lin, -20.f), 20.f);
        float dt = softplusf(lin);
        dt = fminf(fmaxf(dt, 0.001f), 0.1f);
        float Ad = -expf(log_A[k]) * dt;
        Ad = fminf(fmaxf(Ad, -20.f), 0.f);
        const float dec = expf(Ad);

        const float theta = 0.001f + (3.0f - 0.001f) * sigm(theta_raw[k * HH + lane]);
        const float ks = kval * phase_scale[k];
        const float phi = ks / (1.0f + fabsf(ks)) * theta;
        const float kvw = kval * dt;
        float sphi, cphi;
        sincosf(phi, &sphi, &cphi);
        const float re = kvw * cphi;
        const float im = kvw * sphi;

        const size_t base = (((size_t)(b * KK + k)) * LL + t) * 128;
        stack[base + lane] = re;
        stack[base + 64 + lane] = im;
        if (lane == 0) decay[((size_t)(b * KK + k)) * LL + t] = dec;
    }
}

// ---------------- scan phase A: in-place local scan + cumprod ----------------
__launch_bounds__(128)
__global__ void scan_a(float* __restrict__ stack, const float* __restrict__ decay,
                       float* __restrict__ pcum, float* __restrict__ cend,
                       float* __restrict__ cp) {
    const int bk = blockIdx.x / NCHUNK;
    const int chunk = blockIdx.x % NCHUNK;
    const int c = threadIdx.x;
    const size_t rowbase = (size_t)bk * LL + chunk * LCHUNK;
    float acc = 0.f, P = 1.f;
    #pragma unroll 4
    for (int tt = 0; tt < LCHUNK; ++tt) {
        const size_t r = rowbase + tt;
        const float d = decay[r];
        const float x = stack[r * 128 + c];
        acc = fmaf(d, acc, x);
        P *= d;
        stack[r * 128 + c] = acc;
        if (c == 0) pcum[r] = P;
    }
    cend[(size_t)blockIdx.x * 128 + c] = acc;
    if (c == 0) cp[blockIdx.x] = P;
}

// ---------------- scan phase B: carry propagation across chunks ----------------
__launch_bounds__(128)
__global__ void scan_b(const float* __restrict__ cend, const float* __restrict__ cp,
                       float* __restrict__ carry) {
    const int bk = blockIdx.x;
    const int c = threadIdx.x;
    float cur = 0.f;
    for (int ch = 0; ch < NCHUNK; ++ch) {
        const size_t idx = (size_t)bk * NCHUNK + ch;
        carry[idx * 128 + c] = cur;
        cur = fmaf(cp[idx], cur, cend[idx * 128 + c]);
    }
}

// ---------------- combine: scan fixup, q-match, gate matvec, rms -> oc_n ----------------
__launch_bounds__(256)
__global__ void combine_kernel(const float* __restrict__ stack, const float* __restrict__ pcum,
                               const float* __restrict__ carry, const float* __restrict__ qbuf,
                               const float* __restrict__ Z, const float* __restrict__ w_int_raw,
                               const float* __restrict__ W_gate, const float* __restrict__ gn_weight,
                               float* __restrict__ ocn) {
    __shared__ float g_sh[KK * 2 * HH];  // 1536
    __shared__ float gl[KK];
    __shared__ float red[8];
    const int tok = blockIdx.x;
    const int b = tok / LL, t = tok % LL;
    const int tid = threadIdx.x;
    const int chunk = t / LCHUNK;

    if (tid < KK) gl[tid] = Z[(size_t)tok * DIM_TOTAL + DIM_CONV + DIM_SKIP + tid];
    __syncthreads();

    float part = 0.f;
    #pragma unroll
    for (int it = 0; it < 3; ++it) {
        const int p = tid + it * 256;          // 0..767
        const int k = p >> 6, h = p & 63;
        const int kq = k >> 1;
        const size_t bkL = (size_t)(b * KK + k) * LL + t;
        const size_t base = bkL * 128;
        const float pc = pcum[bkL];
        const size_t cbase = ((size_t)(b * KK + k) * NCHUNK + chunk) * 128;
        const float re = fmaf(pc, carry[cbase + h], stack[base + h]);
        const float im = fmaf(pc, carry[cbase + 64 + h], stack[base + 64 + h]);
        const float2 q2 = *reinterpret_cast<const float2*>(&qbuf[(size_t)tok * DIM_Q + kq * 128 + 2 * h]);
        const float qre = q2.x, qim = q2.y;
        float wr = w_int_raw[k * HH + h];
        wr = fminf(fmaxf(wr, -5.f), 5.f);
        const float wint = expf(wr);
        const float ore = (re * qre + im * qim) * wint;
        const float oim = (im * qre - re * qim) * wint;
        // gate = sigmoid(gate_logits @ W_gate)
        float gr = 0.f, gi = 0.f;
        const int cre = k * 128 + h, cim = k * 128 + 64 + h;
        #pragma unroll
        for (int i = 0; i < KK; ++i) {
            gr = fmaf(gl[i], W_gate[i * (KK * 2 * HH) + cre], gr);
            gi = fmaf(gl[i], W_gate[i * (KK * 2 * HH) + cim], gi);
        }
        const float g_re = ore * sigm(gr);
        const float g_im = oim * sigm(gi);
        g_sh[cre] = g_re;
        g_sh[cim] = g_im;
        part = fmaf(g_re, g_re, part);
        part = fmaf(g_im, g_im, part);
    }
    const float ss = blockReduceSum256(part, red);
    const float rs = rsqrtf(ss / (float)(KK * 2 * HH) + 1e-6f);
    __syncthreads();
    #pragma unroll
    for (int it = 0; it < 6; ++it) {
        const int c = tid + it * 256;
        ocn[(size_t)tok * (KK * 2 * HH) + c] = g_sh[c] * rs * gn_weight[c];
    }
}

// ---------------- GEMM2 fused: y_spec + y_skip, then val*silu(gate) ----------------
// grid: (TP/64, 192/64, KK); block 256
__launch_bounds__(256)
__global__ void gemm2_fused(const float* __restrict__ OCN, const float* __restrict__ Z,
                            const float* __restrict__ Wr, const float* __restrict__ Wskip,
                            float* __restrict__ Y) {
    __shared__ float As[8][64];
    __shared__ float Bv[8][64];
    __shared__ float Bg[8][64];
    const int tid = threadIdx.x;
    const int m0 = blockIdx.x * 64;
    const int n0 = blockIdx.y * 64;   // n' in [0,192)
    const int k = blockIdx.z;
    const int tx = tid & 15, ty = tid >> 4;
    const int aRow = tid >> 2, aCol = (tid & 3) * 2;
    const int bRow = tid >> 5, bCol = (tid & 31) * 2;
    float accV[4][4] = {};
    float accG[4][4] = {};

    // segment 1: A = OCN[:, k*128 + f] (f<128), B = W_readout[k]
    for (int k0 = 0; k0 < 128; k0 += 8) {
        const float2 a2 = *reinterpret_cast<const float2*>(
            &OCN[(size_t)(m0 + aRow) * (KK * 2 * HH) + k * 128 + k0 + aCol]);
        As[aCol + 0][aRow] = a2.x; As[aCol + 1][aRow] = a2.y;
        const size_t wr_row = ((size_t)k * 128 + k0 + bRow) * DIM_SWH;
        const float2 bv = *reinterpret_cast<const float2*>(&Wr[wr_row + n0 + bCol]);
        const float2 bg = *reinterpret_cast<const float2*>(&Wr[wr_row + 192 + n0 + bCol]);
        *(float2*)&Bv[bRow][bCol] = bv;
        *(float2*)&Bg[bRow][bCol] = bg;
        __syncthreads();
        #pragma unroll
        for (int kk = 0; kk < 8; ++kk) {
            float af[4], bvf[4], bgf[4];
            *(float4*)af  = *(float4*)&As[kk][ty * 4];
            *(float4*)bvf = *(float4*)&Bv[kk][tx * 4];
            *(float4*)bgf = *(float4*)&Bg[kk][tx * 4];
            #pragma unroll
            for (int i = 0; i < 4; ++i)
                #pragma unroll
                for (int j = 0; j < 4; ++j) {
                    accV[i][j] = fmaf(af[i], bvf[j], accV[i][j]);
                    accG[i][j] = fmaf(af[i], bgf[j], accG[i][j]);
                }
        }
        __syncthreads();
    }
    // segment 2: A = c_skip = Z[:, 1548 + f] (f<192), B = W_skip[:, k*384 + n]
    for (int k0 = 0; k0 < 192; k0 += 8) {
        const float2 a2 = *reinterpret_cast<const float2*>(
            &Z[(size_t)(m0 + aRow) * DIM_TOTAL + DIM_CONV + k0 + aCol]);
        As[aCol + 0][aRow] = a2.x; As[aCol + 1][aRow] = a2.y;
        const size_t ws_row = (size_t)(k0 + bRow) * (KK * DIM_SWH) + k * DIM_SWH;
        const float2 bv = *reinterpret_cast<const float2*>(&Wskip[ws_row + n0 + bCol]);
        const float2 bg = *reinterpret_cast<const float2*>(&Wskip[ws_row + 192 + n0 + bCol]);
        *(float2*)&Bv[bRow][bCol] = bv;
        *(float2*)&Bg[bRow][bCol] = bg;
        __syncthreads();
        #pragma unroll
        for (int kk = 0; kk < 8; ++kk) {
            float af[4], bvf[4], bgf[4];
            *(float4*)af  = *(float4*)&As[kk][ty * 4];
            *(float4*)bvf = *(float4*)&Bv[kk][tx * 4];
            *(float4*)bgf = *(float4*)&Bg[kk][tx * 4];
            #pragma unroll
            for (int i = 0; i < 4; ++i)
                #pragma unroll
                for (int j = 0; j < 4; ++j) {
                    accV[i][j] = fmaf(af[i], bvf[j], accV[i][j]);
                    accG[i][j] = fmaf(af[i], bgf[j], accG[i][j]);
                }
        }
        __syncthreads();
    }
    // epilogue: y = val * silu(gate)
    #pragma unroll
    for (int i = 0; i < 4; ++i) {
        const int tok = m0 + ty * 4 + i;
        float4 out;
        float* op = &out.x;
        #pragma unroll
        for (int j = 0; j < 4; ++j) {
            const float g = accG[i][j];
            op[j] = accV[i][j] * (g * sigm(g));
        }
        const int col = k * 192 + n0 + tx * 4;
        *reinterpret_cast<float4*>(&Y[(size_t)tok * (KK * 192) + col]) = out;
    }
}

// ---------------- launch ----------------
// Workspace footprint per pass of TP tokens (BP = TP/LL batches):
//   Z(TP*1752) | stack(TP*1536) | qbuf(TP*768) | decay(TP*12) | pcum(TP*12)
//   | cend(BP*12*32*128) | cp(BP*12*32) | carry(BP*12*32*128) | ocn(TP*1536)   (floats)
// Y (TP*2304 floats) aliases stack+qbuf (exactly TP*2304), which are dead by gemm2.
static inline size_t pass_need_bytes(int TP) {
    const size_t BP = (size_t)TP / LL;
    size_t total = 0;
    total += (size_t)TP * DIM_TOTAL * 4;        // Z
    total += (size_t)TP * 1536 * 4;             // stack
    total += (size_t)TP * 768 * 4;              // qbuf
    total += (size_t)TP * 12 * 4;               // decay
    total += (size_t)TP * 12 * 4;               // pcum
    total += BP * 12 * NCHUNK * 128 * 4;        // cend
    total += BP * 12 * NCHUNK * 4;              // cp
    total += BP * 12 * NCHUNK * 128 * 4;        // carry
    total += (size_t)TP * 1536 * 4;             // ocn
    return total;
}

extern "C" void kernel_launch(void* const* d_in, const int* in_sizes, int n_in,
                              void* d_out, int out_size, void* d_ws, size_t ws_size,
                              hipStream_t stream) {
    const float* x           = (const float*)d_in[0];
    const float* W_in        = (const float*)d_in[1];
    const float* conv_w      = (const float*)d_in[2];
    const float* wk          = (const float*)d_in[3];
    const float* wq          = (const float*)d_in[4];
    const float* theta_raw   = (const float*)d_in[5];
    const float* w_int_raw   = (const float*)d_in[6];
    const float* dt_scale    = (const float*)d_in[7];
    const float* dt_bias     = (const float*)d_in[8];
    const float* log_A       = (const float*)d_in[9];
    const float* phase_scale = (const float*)d_in[10];
    const float* W_gate      = (const float*)d_in[11];
    const float* gn_weight   = (const float*)d_in[12];
    const float* W_readout   = (const float*)d_in[13];
    const float* W_skip      = (const float*)d_in[14];
    const float* W_out       = (const float*)d_in[15];
    float* out = (float*)d_out;

    // pick the fewest sequential batch-passes that fit in d_ws (deterministic: ws_size is fixed)
    int passes = 4;
    if (ws_size >= pass_need_bytes(TTOK))       passes = 1;
    else if (ws_size >= pass_need_bytes(TTOK/2)) passes = 2;

    const int BP = BB / passes;       // batches per pass
    const int TP = BP * LL;           // tokens per pass

    char* wsb = (char*)d_ws;
    const size_t zB     = (size_t)TP * DIM_TOTAL * 4;
    const size_t stackB = (size_t)TP * 1536 * 4;
    const size_t qB     = (size_t)TP * 768 * 4;
    const size_t dB     = (size_t)TP * 12 * 4;
    const size_t cendB  = (size_t)BP * 12 * NCHUNK * 128 * 4;
    const size_t cpB    = (size_t)BP * 12 * NCHUNK * 4;

    float* Z     = (float*)(wsb);
    float* stack = (float*)(wsb + zB);
    float* qbuf  = (float*)(wsb + zB + stackB);                    // contiguous after stack (Y alias!)
    float* decay = (float*)(wsb + zB + stackB + qB);
    float* pcum  = (float*)(wsb + zB + stackB + qB + dB);
    float* cend  = (float*)(wsb + zB + stackB + qB + 2 * dB);
    float* cp    = (float*)(wsb + zB + stackB + qB + 2 * dB + cendB);
    float* carry = (float*)(wsb + zB + stackB + qB + 2 * dB + cendB + cpB);
    float* ocn   = (float*)(wsb + zB + stackB + qB + 2 * dB + 2 * cendB + cpB);
    float* Y     = stack;   // aliases stack+qbuf = TP*2304 floats, dead after combine

    for (int pass = 0; pass < passes; ++pass) {
        const float* xp  = x   + (size_t)pass * TP * DD;
        float*       op  = out + (size_t)pass * TP * DD;

        // 1. z_all = x @ W_in   [TP,768]@[768,1752]
        sgemm128<<<dim3(TP / 128, (DIM_TOTAL + 127) / 128), 256, 0, stream>>>(
            xp, W_in, Z, TP, DIM_TOTAL, DD);

        // 2. conv + features
        feat_kernel<<<TP, 256, 0, stream>>>(Z, conv_w, wk, wq, theta_raw, dt_scale,
                                            dt_bias, log_A, phase_scale, stack, decay, qbuf);

        // 3-4. chunked scan
        scan_a<<<BP * KK * NCHUNK, 128, 0, stream>>>(stack, decay, pcum, cend, cp);
        scan_b<<<BP * KK, 128, 0, stream>>>(cend, cp, carry);

        // 5. combine -> oc_n
        combine_kernel<<<TP, 256, 0, stream>>>(stack, pcum, carry, qbuf, Z, w_int_raw,
                                               W_gate, gn_weight, ocn);

        // 6. y = val*silu(gate) of (oc_n@W_readout + c_skip@W_skip)   (Y overwrites stack+qbuf)
        gemm2_fused<<<dim3(TP / 64, 3, KK), 256, 0, stream>>>(ocn, Z, W_readout, W_skip, Y);

        // 7. out = y @ W_out   [TP,2304]@[2304,768]
        sgemm128<<<dim3(TP / 128, DD / 128), 256, 0, stream>>>(Y, W_out, op, TP, DD, KK * 3 * HH);
    }
}

// Round 4
// 1118.835 us; speedup vs baseline: 2.1155x; 2.1155x over previous
//
#include <hip/hip_runtime.h>
#include <hip/hip_bf16.h>
#include <cstdint>
#include <cstddef>

// ---------------- problem constants ----------------
#define BB 4
#define LL 4096
#define DD 768
#define KK 12
#define HH 64
#define KSZ 4
#define DIM_MEM 768
#define DIM_MEMT 780
#define DIM_Q 768
#define DIM_CONV 1548
#define DIM_SKIP 192
#define DIM_SWH 384
#define DIM_TOTAL 1752
#define TTOK (BB*LL)
#define NCHUNK 32
#define LCHUNK 128
#define N1REAL 1752
#define N1PAD 1792

typedef unsigned short ushort_t;
typedef __attribute__((ext_vector_type(8))) short short8v;   // 8 x bf16 (4 VGPRs)
typedef __attribute__((ext_vector_type(4))) float f32x4;

// ---------------- helpers ----------------
__device__ __forceinline__ float sigm(float x) { return 1.0f / (1.0f + expf(-x)); }
__device__ __forceinline__ float softplusf(float x) {
    return (x > 0.f) ? (x + log1pf(expf(-x))) : log1pf(expf(x));
}
__device__ __forceinline__ ushort_t f2bf(float f) {
    __hip_bfloat16 h = __float2bfloat16(f);
    return __builtin_bit_cast(ushort_t, h);
}
__device__ __forceinline__ float blockReduceSum256(float v, float* sbuf) {
    #pragma unroll
    for (int off = 32; off > 0; off >>= 1) v += __shfl_xor(v, off);
    const int wid = threadIdx.x >> 6;
    __syncthreads();
    if ((threadIdx.x & 63) == 0) sbuf[wid] = v;
    __syncthreads();
    return sbuf[0] + sbuf[1] + sbuf[2] + sbuf[3];
}
__device__ __forceinline__ void gload_lds16(const void* g, void* l) {
    __builtin_amdgcn_global_load_lds(
        (const __attribute__((address_space(1))) void*)g,
        (__attribute__((address_space(3))) void*)l, 16, 0, 0);
}

// ---------------- cast fp32 -> bf16 (vectorized) ----------------
__launch_bounds__(256)
__global__ void cast_bf16(const float* __restrict__ in, ushort_t* __restrict__ out, int n4) {
    const int stride = gridDim.x * 256;
    for (int i = blockIdx.x * 256 + threadIdx.x; i < n4; i += stride) {
        const float4 v = reinterpret_cast<const float4*>(in)[i];
        ushort4 o;
        o.x = f2bf(v.x); o.y = f2bf(v.y); o.z = f2bf(v.z); o.w = f2bf(v.w);
        reinterpret_cast<ushort4*>(out)[i] = o;
    }
}

// ---------------- transpose + cast: in[R][Cc] f32 -> out[Cpad][R] bf16 (zero pad) ----------------
__global__ void transpose_cast(const float* __restrict__ in, ushort_t* __restrict__ out,
                               int R, int Cc, int Cpad) {
    __shared__ float tile[32][33];
    const int tx = threadIdx.x, ty = threadIdx.y;
    const int c0 = blockIdx.x * 32, r0 = blockIdx.y * 32;
    #pragma unroll
    for (int rr = ty; rr < 32; rr += 8) {
        const int r = r0 + rr, c = c0 + tx;
        tile[rr][tx] = (r < R && c < Cc) ? in[(size_t)r * Cc + c] : 0.f;
    }
    __syncthreads();
    #pragma unroll
    for (int rr = ty; rr < 32; rr += 8) {
        const int c = c0 + rr, r = r0 + tx;
        if (c < Cpad && r < R)
            out[(size_t)c * R + r] = f2bf(tile[tx][rr]);
    }
}

// ---------------- bf16 MFMA GEMM: C[M,Nreal] f32 = A[M,K]bf16 @ Bt[Npad,K]bf16^T ----------------
// grid (M/128, Npad/128), block 256 (4 waves). K % 64 == 0. m97-style: 128^2 tile, BK=64,
// double-buffered LDS, global_load_lds width-16 staging, 2-barrier loop.
__launch_bounds__(256)
__global__ void mfma_gemm(const ushort_t* __restrict__ A, const ushort_t* __restrict__ Bt,
                          float* __restrict__ C, int Nreal, int K) {
    __shared__ ushort_t As[2][128 * 64];
    __shared__ ushort_t Bs[2][128 * 64];
    const int tid = threadIdx.x;
    const int lane = tid & 63, w = tid >> 6;
    const int m0 = blockIdx.x * 128, n0 = blockIdx.y * 128;
    const int wm = w & 1, wn = w >> 1;
    const int nkt = K >> 6;
    const int lrow = lane >> 3;          // 0..7
    const int lcol = (lane & 7) * 8;     // 0,8,..,56

    f32x4 acc[4][4] = {};

    auto stage = [&](int buf, int k0) {
        #pragma unroll
        for (int i = 0; i < 4; ++i) {
            const int seg = w * 4 + i;               // 0..15
            const int row = seg * 8 + lrow;          // 0..127
            gload_lds16(&A[(size_t)(m0 + row) * K + k0 + lcol], &As[buf][seg * 512]);
            gload_lds16(&Bt[(size_t)(n0 + row) * K + k0 + lcol], &Bs[buf][seg * 512]);
        }
    };

    stage(0, 0);
    for (int kt = 0; kt < nkt; ++kt) {
        const int cur = kt & 1;
        __syncthreads();                              // drains vmcnt for buf 'cur'
        if (kt + 1 < nkt) stage(cur ^ 1, (kt + 1) << 6);
        #pragma unroll
        for (int kk = 0; kk < 2; ++kk) {
            short8v a[4], b[4];
            #pragma unroll
            for (int i = 0; i < 4; ++i)
                a[i] = *(const short8v*)&As[cur][(wm * 64 + i * 16 + (lane & 15)) * 64 + kk * 32 + (lane >> 4) * 8];
            #pragma unroll
            for (int j = 0; j < 4; ++j)
                b[j] = *(const short8v*)&Bs[cur][(wn * 64 + j * 16 + (lane & 15)) * 64 + kk * 32 + (lane >> 4) * 8];
            #pragma unroll
            for (int i = 0; i < 4; ++i)
                #pragma unroll
                for (int j = 0; j < 4; ++j)
                    acc[i][j] = __builtin_amdgcn_mfma_f32_16x16x32_bf16(a[i], b[j], acc[i][j], 0, 0, 0);
        }
    }
    #pragma unroll
    for (int i = 0; i < 4; ++i) {
        const int rbase = m0 + wm * 64 + i * 16 + (lane >> 4) * 4;
        #pragma unroll
        for (int j = 0; j < 4; ++j) {
            const int col = n0 + wn * 64 + j * 16 + (lane & 15);
            if (col < Nreal) {
                #pragma unroll
                for (int r = 0; r < 4; ++r)
                    C[(size_t)(rbase + r) * Nreal + col] = acc[i][j][r];
            }
        }
    }
}

// ---------------- feature kernel ----------------
__launch_bounds__(256)
__global__ void feat_kernel(const float* __restrict__ Z, const float* __restrict__ conv_w,
                            const float* __restrict__ wk, const float* __restrict__ wq,
                            const float* __restrict__ theta_raw, const float* __restrict__ dt_scale,
                            const float* __restrict__ dt_bias, const float* __restrict__ log_A,
                            const float* __restrict__ phase_scale,
                            float* __restrict__ stack, float* __restrict__ decay,
                            float* __restrict__ qbuf) {
    __shared__ float zc[DIM_CONV];
    __shared__ float red[8];
    const int tok = blockIdx.x;
    const int b = tok / LL, t = tok % LL;
    const int tid = threadIdx.x;

    for (int c = tid; c < DIM_CONV; c += 256) {
        float s = 0.f;
        #pragma unroll
        for (int j = 0; j < KSZ; ++j) {
            const int tt = t + j - (KSZ - 1);
            if (tt >= 0)
                s = fmaf(conv_w[j * DIM_CONV + c], Z[((size_t)(b * LL + tt)) * DIM_TOTAL + c], s);
        }
        zc[c] = s * sigm(s);
    }
    __syncthreads();

    float part = 0.f;
    #pragma unroll
    for (int it = 0; it < 3; ++it) {
        const float v = zc[DIM_MEMT + tid + it * 256];
        part = fmaf(v, v, part);
    }
    const float qss = blockReduceSum256(part, red);
    const float qrs = rsqrtf(qss / (float)DIM_Q + 1e-6f);
    #pragma unroll
    for (int it = 0; it < 3; ++it) {
        const int c = tid + it * 256;
        qbuf[(size_t)tok * DIM_Q + c] = zc[DIM_MEMT + c] * qrs * wq[c];
    }

    const int wave = tid >> 6, lane = tid & 63;
    for (int k = wave; k < KK; k += 4) {
        const float v = zc[k * HH + lane];
        float ss = v * v;
        #pragma unroll
        for (int off = 32; off > 0; off >>= 1) ss += __shfl_xor(ss, off);
        const float rs = rsqrtf(ss / (float)HH + 1e-6f);
        const float kval = v * rs * wk[lane];

        const float sraw = zc[DIM_MEM + k];
        float lin = fmaf(dt_scale[k], sraw, dt_bias[k]);
        lin = fminf(fmaxf(lin, -20.f), 20.f);
        float dt = softplusf(lin);
        dt = fminf(fmaxf(dt, 0.001f), 0.1f);
        float Ad = -expf(log_A[k]) * dt;
        Ad = fminf(fmaxf(Ad, -20.f), 0.f);
        const float dec = expf(Ad);

        const float theta = 0.001f + (3.0f - 0.001f) * sigm(theta_raw[k * HH + lane]);
        const float ks = kval * phase_scale[k];
        const float phi = ks / (1.0f + fabsf(ks)) * theta;
        const float kvw = kval * dt;
        float sphi, cphi;
        sincosf(phi, &sphi, &cphi);

        const size_t base = (((size_t)(b * KK + k)) * LL + t) * 128;
        stack[base + lane] = kvw * cphi;
        stack[base + 64 + lane] = kvw * sphi;
        if (lane == 0) decay[((size_t)(b * KK + k)) * LL + t] = dec;
    }
}

// ---------------- scan phase A ----------------
__launch_bounds__(128)
__global__ void scan_a(float* __restrict__ stack, const float* __restrict__ decay,
                       float* __restrict__ pcum, float* __restrict__ cend,
                       float* __restrict__ cp) {
    const int bk = blockIdx.x / NCHUNK;
    const int chunk = blockIdx.x % NCHUNK;
    const int c = threadIdx.x;
    const size_t rowbase = (size_t)bk * LL + chunk * LCHUNK;
    float acc = 0.f, P = 1.f;
    #pragma unroll 4
    for (int tt = 0; tt < LCHUNK; ++tt) {
        const size_t r = rowbase + tt;
        const float d = decay[r];
        const float x = stack[r * 128 + c];
        acc = fmaf(d, acc, x);
        P *= d;
        stack[r * 128 + c] = acc;
        if (c == 0) pcum[r] = P;
    }
    cend[(size_t)blockIdx.x * 128 + c] = acc;
    if (c == 0) cp[blockIdx.x] = P;
}

// ---------------- scan phase B ----------------
__launch_bounds__(128)
__global__ void scan_b(const float* __restrict__ cend, const float* __restrict__ cp,
                       float* __restrict__ carry) {
    const int bk = blockIdx.x;
    const int c = threadIdx.x;
    float cur = 0.f;
    for (int ch = 0; ch < NCHUNK; ++ch) {
        const size_t idx = (size_t)bk * NCHUNK + ch;
        carry[idx * 128 + c] = cur;
        cur = fmaf(cp[idx], cur, cend[idx * 128 + c]);
    }
}

// ---------------- combine ----------------
__launch_bounds__(256)
__global__ void combine_kernel(const float* __restrict__ stack, const float* __restrict__ pcum,
                               const float* __restrict__ carry, const float* __restrict__ qbuf,
                               const float* __restrict__ Z, const float* __restrict__ w_int_raw,
                               const float* __restrict__ W_gate, const float* __restrict__ gn_weight,
                               float* __restrict__ ocn) {
    __shared__ float g_sh[KK * 2 * HH];
    __shared__ float gl[KK];
    __shared__ float red[8];
    const int tok = blockIdx.x;
    const int b = tok / LL, t = tok % LL;
    const int tid = threadIdx.x;
    const int chunk = t / LCHUNK;

    if (tid < KK) gl[tid] = Z[(size_t)tok * DIM_TOTAL + DIM_CONV + DIM_SKIP + tid];
    __syncthreads();

    float part = 0.f;
    #pragma unroll
    for (int it = 0; it < 3; ++it) {
        const int p = tid + it * 256;
        const int k = p >> 6, h = p & 63;
        const int kq = k >> 1;
        const size_t bkL = (size_t)(b * KK + k) * LL + t;
        const size_t base = bkL * 128;
        const float pc = pcum[bkL];
        const size_t cbase = ((size_t)(b * KK + k) * NCHUNK + chunk) * 128;
        const float re = fmaf(pc, carry[cbase + h], stack[base + h]);
        const float im = fmaf(pc, carry[cbase + 64 + h], stack[base + 64 + h]);
        const float2 q2 = *reinterpret_cast<const float2*>(&qbuf[(size_t)tok * DIM_Q + kq * 128 + 2 * h]);
        float wr = w_int_raw[k * HH + h];
        wr = fminf(fmaxf(wr, -5.f), 5.f);
        const float wint = expf(wr);
        const float ore = (re * q2.x + im * q2.y) * wint;
        const float oim = (im * q2.x - re * q2.y) * wint;
        float gr = 0.f, gi = 0.f;
        const int cre = k * 128 + h, cim = k * 128 + 64 + h;
        #pragma unroll
        for (int i = 0; i < KK; ++i) {
            gr = fmaf(gl[i], W_gate[i * (KK * 2 * HH) + cre], gr);
            gi = fmaf(gl[i], W_gate[i * (KK * 2 * HH) + cim], gi);
        }
        const float g_re = ore * sigm(gr);
        const float g_im = oim * sigm(gi);
        g_sh[cre] = g_re;
        g_sh[cim] = g_im;
        part = fmaf(g_re, g_re, part);
        part = fmaf(g_im, g_im, part);
    }
    const float ss = blockReduceSum256(part, red);
    const float rs = rsqrtf(ss / (float)(KK * 2 * HH) + 1e-6f);
    __syncthreads();
    #pragma unroll
    for (int it = 0; it < 6; ++it) {
        const int c = tid + it * 256;
        ocn[(size_t)tok * (KK * 2 * HH) + c] = g_sh[c] * rs * gn_weight[c];
    }
}

// ---------------- GEMM2 fused (fp32) -> Y bf16 ----------------
__launch_bounds__(256)
__global__ void gemm2_fused(const float* __restrict__ OCN, const float* __restrict__ Z,
                            const float* __restrict__ Wr, const float* __restrict__ Wskip,
                            ushort_t* __restrict__ Y) {
    __shared__ float As[8][64];
    __shared__ float Bv[8][64];
    __shared__ float Bg[8][64];
    const int tid = threadIdx.x;
    const int m0 = blockIdx.x * 64;
    const int n0 = blockIdx.y * 64;
    const int k = blockIdx.z;
    const int tx = tid & 15, ty = tid >> 4;
    const int aRow = tid >> 2, aCol = (tid & 3) * 2;
    const int bRow = tid >> 5, bCol = (tid & 31) * 2;
    float accV[4][4] = {};
    float accG[4][4] = {};

    for (int k0 = 0; k0 < 128; k0 += 8) {
        const float2 a2 = *reinterpret_cast<const float2*>(
            &OCN[(size_t)(m0 + aRow) * (KK * 2 * HH) + k * 128 + k0 + aCol]);
        As[aCol + 0][aRow] = a2.x; As[aCol + 1][aRow] = a2.y;
        const size_t wr_row = ((size_t)k * 128 + k0 + bRow) * DIM_SWH;
        *(float2*)&Bv[bRow][bCol] = *reinterpret_cast<const float2*>(&Wr[wr_row + n0 + bCol]);
        *(float2*)&Bg[bRow][bCol] = *reinterpret_cast<const float2*>(&Wr[wr_row + 192 + n0 + bCol]);
        __syncthreads();
        #pragma unroll
        for (int kk = 0; kk < 8; ++kk) {
            float af[4], bvf[4], bgf[4];
            *(float4*)af  = *(float4*)&As[kk][ty * 4];
            *(float4*)bvf = *(float4*)&Bv[kk][tx * 4];
            *(float4*)bgf = *(float4*)&Bg[kk][tx * 4];
            #pragma unroll
            for (int i = 0; i < 4; ++i)
                #pragma unroll
                for (int j = 0; j < 4; ++j) {
                    accV[i][j] = fmaf(af[i], bvf[j], accV[i][j]);
                    accG[i][j] = fmaf(af[i], bgf[j], accG[i][j]);
                }
        }
        __syncthreads();
    }
    for (int k0 = 0; k0 < 192; k0 += 8) {
        const float2 a2 = *reinterpret_cast<const float2*>(
            &Z[(size_t)(m0 + aRow) * DIM_TOTAL + DIM_CONV + k0 + aCol]);
        As[aCol + 0][aRow] = a2.x; As[aCol + 1][aRow] = a2.y;
        const size_t ws_row = (size_t)(k0 + bRow) * (KK * DIM_SWH) + k * DIM_SWH;
        *(float2*)&Bv[bRow][bCol] = *reinterpret_cast<const float2*>(&Wskip[ws_row + n0 + bCol]);
        *(float2*)&Bg[bRow][bCol] = *reinterpret_cast<const float2*>(&Wskip[ws_row + 192 + n0 + bCol]);
        __syncthreads();
        #pragma unroll
        for (int kk = 0; kk < 8; ++kk) {
            float af[4], bvf[4], bgf[4];
            *(float4*)af  = *(float4*)&As[kk][ty * 4];
            *(float4*)bvf = *(float4*)&Bv[kk][tx * 4];
            *(float4*)bgf = *(float4*)&Bg[kk][tx * 4];
            #pragma unroll
            for (int i = 0; i < 4; ++i)
                #pragma unroll
                for (int j = 0; j < 4; ++j) {
                    accV[i][j] = fmaf(af[i], bvf[j], accV[i][j]);
                    accG[i][j] = fmaf(af[i], bgf[j], accG[i][j]);
                }
        }
        __syncthreads();
    }
    #pragma unroll
    for (int i = 0; i < 4; ++i) {
        const int tok = m0 + ty * 4 + i;
        ushort4 o;
        ushort_t* op = &o.x;
        #pragma unroll
        for (int j = 0; j < 4; ++j) {
            const float g = accG[i][j];
            op[j] = f2bf(accV[i][j] * (g * sigm(g)));
        }
        const int col = k * 192 + n0 + tx * 4;
        *reinterpret_cast<ushort4*>(&Y[(size_t)tok * (KK * 3 * HH) + col]) = o;
    }
}

// ---------------- launch ----------------
static inline size_t pass_need_bytes(int TP) {
    const size_t BP = (size_t)TP / LL;
    size_t total = 0;
    total += (size_t)TP * DIM_TOTAL * 4;        // Z
    total += (size_t)TP * 1536 * 4;             // stack (also: W_inT, then Y bf16)
    total += (size_t)TP * 768 * 4;              // qbuf  (also: xb bf16, then W_outT)
    total += (size_t)TP * 12 * 4;               // decay
    total += (size_t)TP * 12 * 4;               // pcum
    total += BP * 12 * NCHUNK * 128 * 4;        // cend
    total += BP * 12 * NCHUNK * 4;              // cp
    total += BP * 12 * NCHUNK * 128 * 4;        // carry
    total += (size_t)TP * 1536 * 4;             // ocn
    return total;
}

extern "C" void kernel_launch(void* const* d_in, const int* in_sizes, int n_in,
                              void* d_out, int out_size, void* d_ws, size_t ws_size,
                              hipStream_t stream) {
    const float* x           = (const float*)d_in[0];
    const float* W_in        = (const float*)d_in[1];
    const float* conv_w      = (const float*)d_in[2];
    const float* wk          = (const float*)d_in[3];
    const float* wq          = (const float*)d_in[4];
    const float* theta_raw   = (const float*)d_in[5];
    const float* w_int_raw   = (const float*)d_in[6];
    const float* dt_scale    = (const float*)d_in[7];
    const float* dt_bias     = (const float*)d_in[8];
    const float* log_A       = (const float*)d_in[9];
    const float* phase_scale = (const float*)d_in[10];
    const float* W_gate      = (const float*)d_in[11];
    const float* gn_weight   = (const float*)d_in[12];
    const float* W_readout   = (const float*)d_in[13];
    const float* W_skip      = (const float*)d_in[14];
    const float* W_out       = (const float*)d_in[15];
    float* out = (float*)d_out;

    int passes = 4;
    if (ws_size >= pass_need_bytes(TTOK))        passes = 1;
    else if (ws_size >= pass_need_bytes(TTOK/2)) passes = 2;

    const int BP = BB / passes;
    const int TP = BP * LL;

    char* wsb = (char*)d_ws;
    const size_t zB     = (size_t)TP * DIM_TOTAL * 4;
    const size_t stackB = (size_t)TP * 1536 * 4;
    const size_t qB     = (size_t)TP * 768 * 4;
    const size_t dB     = (size_t)TP * 12 * 4;
    const size_t cendB  = (size_t)BP * 12 * NCHUNK * 128 * 4;
    const size_t cpB    = (size_t)BP * 12 * NCHUNK * 4;

    float* Z       = (float*)(wsb);
    float* stack   = (float*)(wsb + zB);
    float* qbuf    = (float*)(wsb + zB + stackB);
    float* decay   = (float*)(wsb + zB + stackB + qB);
    float* pcum    = (float*)(wsb + zB + stackB + qB + dB);
    float* cend    = (float*)(wsb + zB + stackB + qB + 2 * dB);
    float* cp      = (float*)(wsb + zB + stackB + qB + 2 * dB + cendB);
    float* carry   = (float*)(wsb + zB + stackB + qB + 2 * dB + cendB + cpB);
    float* ocn     = (float*)(wsb + zB + stackB + qB + 2 * dB + 2 * cendB + cpB);
    // aliases (dead-region reuse; footprint unchanged):
    ushort_t* xb    = (ushort_t*)qbuf;    // [TP][768] bf16, dead after GEMM1 (feat overwrites)
    ushort_t* WinT  = (ushort_t*)stack;   // [1792][768] bf16, dead after GEMM1
    ushort_t* WoutT = (ushort_t*)qbuf;    // [768][2304] bf16, written after combine (qbuf dead)
    ushort_t* Y     = (ushort_t*)stack;   // [TP][2304] bf16, written by gemm2 (stack dead)

    for (int pass = 0; pass < passes; ++pass) {
        const float* xp = x   + (size_t)pass * TP * DD;
        float*       op = out + (size_t)pass * TP * DD;

        // prep: cast x, transpose+cast W_in
        cast_bf16<<<1024, 256, 0, stream>>>(xp, xb, TP * DD / 4);
        transpose_cast<<<dim3(N1PAD / 32, DD / 32), dim3(32, 8), 0, stream>>>(
            W_in, WinT, DD, N1REAL, N1PAD);

        // 1. Z = x @ W_in  (bf16 MFMA)
        mfma_gemm<<<dim3(TP / 128, N1PAD / 128), 256, 0, stream>>>(xb, WinT, Z, N1REAL, DD);

        // 2. conv + features
        feat_kernel<<<TP, 256, 0, stream>>>(Z, conv_w, wk, wq, theta_raw, dt_scale,
                                            dt_bias, log_A, phase_scale, stack, decay, qbuf);

        // 3-4. chunked scan
        scan_a<<<BP * KK * NCHUNK, 128, 0, stream>>>(stack, decay, pcum, cend, cp);
        scan_b<<<BP * KK, 128, 0, stream>>>(cend, cp, carry);

        // 5. combine -> oc_n
        combine_kernel<<<TP, 256, 0, stream>>>(stack, pcum, carry, qbuf, Z, w_int_raw,
                                               W_gate, gn_weight, ocn);

        // prep: transpose+cast W_out into (now dead) qbuf region
        transpose_cast<<<dim3(DD / 32, (KK * 3 * HH) / 32), dim3(32, 8), 0, stream>>>(
            W_out, WoutT, KK * 3 * HH, DD, DD);

        // 6. Y(bf16) = val*silu(gate) of (oc_n@W_readout + c_skip@W_skip)
        gemm2_fused<<<dim3(TP / 64, 3, KK), 256, 0, stream>>>(ocn, Z, W_readout, W_skip, Y);

        // 7. out = Y @ W_out  (bf16 MFMA)
        mfma_gemm<<<dim3(TP / 128, DD / 128), 256, 0, stream>>>(Y, WoutT, op, DD, KK * 3 * HH);
    }
}

// Round 5
// 651.773 us; speedup vs baseline: 3.6315x; 1.7166x over previous
//
#include <hip/hip_runtime.h>
#include <hip/hip_bf16.h>
#include <cstdint>
#include <cstddef>

// ---------------- problem constants ----------------
#define BB 4
#define LL 4096
#define DD 768
#define KK 12
#define HH 64
#define KSZ 4
#define DIM_MEM 768
#define DIM_MEMT 780
#define DIM_Q 768
#define DIM_CONV 1548
#define DIM_SKIP 192
#define DIM_SWH 384
#define DIM_TOTAL 1752
#define TTOK (BB*LL)
#define NCHUNK 32
#define LCHUNK 128
#define N1REAL 1752
#define N1PAD 1792

typedef unsigned short ushort_t;
typedef __attribute__((ext_vector_type(8))) short short8v;   // 8 x bf16 (4 VGPRs)
typedef __attribute__((ext_vector_type(4))) float f32x4;

// ---------------- helpers ----------------
__device__ __forceinline__ float sigm(float x) { return 1.0f / (1.0f + expf(-x)); }
__device__ __forceinline__ float softplusf(float x) {
    return (x > 0.f) ? (x + log1pf(expf(-x))) : log1pf(expf(x));
}
__device__ __forceinline__ ushort_t f2bf(float f) {
    __hip_bfloat16 h = __float2bfloat16(f);
    return __builtin_bit_cast(ushort_t, h);
}
__device__ __forceinline__ float blockReduceSum256(float v, float* sbuf) {
    #pragma unroll
    for (int off = 32; off > 0; off >>= 1) v += __shfl_xor(v, off);
    const int wid = threadIdx.x >> 6;
    __syncthreads();
    if ((threadIdx.x & 63) == 0) sbuf[wid] = v;
    __syncthreads();
    return sbuf[0] + sbuf[1] + sbuf[2] + sbuf[3];
}
__device__ __forceinline__ void gload_lds16(const void* g, void* l) {
    __builtin_amdgcn_global_load_lds(
        (const __attribute__((address_space(1))) void*)g,
        (__attribute__((address_space(3))) void*)l, 16, 0, 0);
}

// ---------------- cast fp32 -> bf16 (vectorized) ----------------
__launch_bounds__(256)
__global__ void cast_bf16(const float* __restrict__ in, ushort_t* __restrict__ out, int n4) {
    const int stride = gridDim.x * 256;
    for (int i = blockIdx.x * 256 + threadIdx.x; i < n4; i += stride) {
        const float4 v = reinterpret_cast<const float4*>(in)[i];
        ushort4 o;
        o.x = f2bf(v.x); o.y = f2bf(v.y); o.z = f2bf(v.z); o.w = f2bf(v.w);
        reinterpret_cast<ushort4*>(out)[i] = o;
    }
}

// ---------------- transpose + cast: in[R][Cc] f32 -> out[Cpad][R] bf16 (zero pad) ----------------
__global__ void transpose_cast(const float* __restrict__ in, ushort_t* __restrict__ out,
                               int R, int Cc, int Cpad) {
    __shared__ float tile[32][33];
    const int tx = threadIdx.x, ty = threadIdx.y;
    const int c0 = blockIdx.x * 32, r0 = blockIdx.y * 32;
    #pragma unroll
    for (int rr = ty; rr < 32; rr += 8) {
        const int r = r0 + rr, c = c0 + tx;
        tile[rr][tx] = (r < R && c < Cc) ? in[(size_t)r * Cc + c] : 0.f;
    }
    __syncthreads();
    #pragma unroll
    for (int rr = ty; rr < 32; rr += 8) {
        const int c = c0 + rr, r = r0 + tx;
        if (c < Cpad && r < R)
            out[(size_t)c * R + r] = f2bf(tile[tx][rr]);
    }
}

// ---------------- build Bt for gemm2: Btv/Btg [12][192][320] bf16 ----------------
// Bt[k][n][kk] : kk<128 -> W_readout[k][kk][n(+192 for gate)]; kk>=128 -> W_skip[kk-128][k*384+n(+192)]
__global__ void prep_bt(const float* __restrict__ Wr, const float* __restrict__ Wskip,
                        ushort_t* __restrict__ Btv, ushort_t* __restrict__ Btg) {
    const int k = blockIdx.x, n = blockIdx.y, kk = threadIdx.x;   // block 320
    float v, g;
    if (kk < 128) {
        const size_t base = ((size_t)k * 128 + kk) * DIM_SWH;
        v = Wr[base + n];
        g = Wr[base + 192 + n];
    } else {
        const size_t base = (size_t)(kk - 128) * (KK * DIM_SWH) + (size_t)k * DIM_SWH;
        v = Wskip[base + n];
        g = Wskip[base + 192 + n];
    }
    const size_t o = ((size_t)k * 192 + n) * 320 + kk;
    Btv[o] = f2bf(v);
    Btg[o] = f2bf(g);
}

// ---------------- bf16 MFMA GEMM: C[M,Nreal] f32 = A[M,K]bf16 @ Bt[Npad,K]bf16^T ----------------
__launch_bounds__(256)
__global__ void mfma_gemm(const ushort_t* __restrict__ A, const ushort_t* __restrict__ Bt,
                          float* __restrict__ C, int Nreal, int K) {
    __shared__ ushort_t As[2][128 * 64];
    __shared__ ushort_t Bs[2][128 * 64];
    const int tid = threadIdx.x;
    const int lane = tid & 63, w = tid >> 6;
    const int m0 = blockIdx.x * 128, n0 = blockIdx.y * 128;
    const int wm = w & 1, wn = w >> 1;
    const int nkt = K >> 6;
    const int lrow = lane >> 3;
    const int lcol = (lane & 7) * 8;

    f32x4 acc[4][4] = {};

    auto stage = [&](int buf, int k0) {
        #pragma unroll
        for (int i = 0; i < 4; ++i) {
            const int seg = w * 4 + i;
            const int row = seg * 8 + lrow;
            gload_lds16(&A[(size_t)(m0 + row) * K + k0 + lcol], &As[buf][seg * 512]);
            gload_lds16(&Bt[(size_t)(n0 + row) * K + k0 + lcol], &Bs[buf][seg * 512]);
        }
    };

    stage(0, 0);
    for (int kt = 0; kt < nkt; ++kt) {
        const int cur = kt & 1;
        __syncthreads();
        if (kt + 1 < nkt) stage(cur ^ 1, (kt + 1) << 6);
        #pragma unroll
        for (int kk = 0; kk < 2; ++kk) {
            short8v a[4], b[4];
            #pragma unroll
            for (int i = 0; i < 4; ++i)
                a[i] = *(const short8v*)&As[cur][(wm * 64 + i * 16 + (lane & 15)) * 64 + kk * 32 + (lane >> 4) * 8];
            #pragma unroll
            for (int j = 0; j < 4; ++j)
                b[j] = *(const short8v*)&Bs[cur][(wn * 64 + j * 16 + (lane & 15)) * 64 + kk * 32 + (lane >> 4) * 8];
            #pragma unroll
            for (int i = 0; i < 4; ++i)
                #pragma unroll
                for (int j = 0; j < 4; ++j)
                    acc[i][j] = __builtin_amdgcn_mfma_f32_16x16x32_bf16(a[i], b[j], acc[i][j], 0, 0, 0);
        }
    }
    #pragma unroll
    for (int i = 0; i < 4; ++i) {
        const int rbase = m0 + wm * 64 + i * 16 + (lane >> 4) * 4;
        #pragma unroll
        for (int j = 0; j < 4; ++j) {
            const int col = n0 + wn * 64 + j * 16 + (lane & 15);
            if (col < Nreal) {
                #pragma unroll
                for (int r = 0; r < 4; ++r)
                    C[(size_t)(rbase + r) * Nreal + col] = acc[i][j][r];
            }
        }
    }
}

// ---------------- gemm2 MFMA: per-k grouped GEMM with fused val*silu(gate) ----------------
// grid (M/128, 192/64, 12), block 256. A = [OCNb_k (K0=128) | CskB (K1=192)], K=320.
// B pair-columns: Btv (val) and Btg (gate), each [192][320] per k.
__launch_bounds__(256)
__global__ void gemm2_mfma(const ushort_t* __restrict__ OCNb, const ushort_t* __restrict__ CskB,
                           const ushort_t* __restrict__ Btv, const ushort_t* __restrict__ Btg,
                           ushort_t* __restrict__ Y) {
    __shared__ ushort_t As[2][128 * 64];
    __shared__ ushort_t Bvs[2][64 * 64];
    __shared__ ushort_t Bgs[2][64 * 64];
    const int tid = threadIdx.x;
    const int lane = tid & 63, w = tid >> 6;
    const int m0 = blockIdx.x * 128;
    const int n0 = blockIdx.y * 64;          // pair-column base (0,64,128)
    const int k  = blockIdx.z;
    const int wm = w & 1, wn = w >> 1;       // 2x2 waves: 64 rows x 32 pair-cols each
    const int lrow = lane >> 3;
    const int lcol = (lane & 7) * 8;
    const ushort_t* btv = Btv + (size_t)k * 192 * 320;
    const ushort_t* btg = Btg + (size_t)k * 192 * 320;

    f32x4 accV[4][2] = {};
    f32x4 accG[4][2] = {};

    auto stage = [&](int buf, int kt) {
        #pragma unroll
        for (int i = 0; i < 4; ++i) {
            const int seg = w * 4 + i;
            const int row = seg * 8 + lrow;
            const ushort_t* src = (kt < 2)
                ? OCNb + (size_t)(m0 + row) * (KK * 2 * HH) + k * 128 + kt * 64 + lcol
                : CskB + (size_t)(m0 + row) * DIM_SKIP + (kt - 2) * 64 + lcol;
            gload_lds16(src, &As[buf][seg * 512]);
        }
        #pragma unroll
        for (int i = 0; i < 2; ++i) {
            const int seg = w * 2 + i;
            const int row = seg * 8 + lrow;
            gload_lds16(btv + (size_t)(n0 + row) * 320 + kt * 64 + lcol, &Bvs[buf][seg * 512]);
            gload_lds16(btg + (size_t)(n0 + row) * 320 + kt * 64 + lcol, &Bgs[buf][seg * 512]);
        }
    };

    stage(0, 0);
    for (int kt = 0; kt < 5; ++kt) {
        const int cur = kt & 1;
        __syncthreads();
        if (kt + 1 < 5) stage(cur ^ 1, kt + 1);
        #pragma unroll
        for (int kk = 0; kk < 2; ++kk) {
            short8v a[4], bv[2], bg[2];
            #pragma unroll
            for (int i = 0; i < 4; ++i)
                a[i] = *(const short8v*)&As[cur][(wm * 64 + i * 16 + (lane & 15)) * 64 + kk * 32 + (lane >> 4) * 8];
            #pragma unroll
            for (int j = 0; j < 2; ++j) {
                bv[j] = *(const short8v*)&Bvs[cur][(wn * 32 + j * 16 + (lane & 15)) * 64 + kk * 32 + (lane >> 4) * 8];
                bg[j] = *(const short8v*)&Bgs[cur][(wn * 32 + j * 16 + (lane & 15)) * 64 + kk * 32 + (lane >> 4) * 8];
            }
            #pragma unroll
            for (int i = 0; i < 4; ++i)
                #pragma unroll
                for (int j = 0; j < 2; ++j) {
                    accV[i][j] = __builtin_amdgcn_mfma_f32_16x16x32_bf16(a[i], bv[j], accV[i][j], 0, 0, 0);
                    accG[i][j] = __builtin_amdgcn_mfma_f32_16x16x32_bf16(a[i], bg[j], accG[i][j], 0, 0, 0);
                }
        }
    }
    // epilogue: y = val * silu(gate), bf16
    #pragma unroll
    for (int i = 0; i < 4; ++i) {
        const int rbase = m0 + wm * 64 + i * 16 + (lane >> 4) * 4;
        #pragma unroll
        for (int j = 0; j < 2; ++j) {
            const int col = k * 192 + n0 + wn * 32 + j * 16 + (lane & 15);
            #pragma unroll
            for (int r = 0; r < 4; ++r) {
                const float g = accG[i][j][r];
                Y[(size_t)(rbase + r) * (KK * 3 * HH) + col] = f2bf(accV[i][j][r] * (g * sigm(g)));
            }
        }
    }
}

// ---------------- feature kernel ----------------
__launch_bounds__(256)
__global__ void feat_kernel(const float* __restrict__ Z, const float* __restrict__ conv_w,
                            const float* __restrict__ wk, const float* __restrict__ wq,
                            const float* __restrict__ theta_raw, const float* __restrict__ dt_scale,
                            const float* __restrict__ dt_bias, const float* __restrict__ log_A,
                            const float* __restrict__ phase_scale,
                            float* __restrict__ stack, float* __restrict__ decay,
                            float* __restrict__ qbuf) {
    __shared__ float zc[DIM_CONV];
    __shared__ float red[8];
    const int tok = blockIdx.x;
    const int b = tok / LL, t = tok % LL;
    const int tid = threadIdx.x;

    for (int c = tid; c < DIM_CONV; c += 256) {
        float s = 0.f;
        #pragma unroll
        for (int j = 0; j < KSZ; ++j) {
            const int tt = t + j - (KSZ - 1);
            if (tt >= 0)
                s = fmaf(conv_w[j * DIM_CONV + c], Z[((size_t)(b * LL + tt)) * DIM_TOTAL + c], s);
        }
        zc[c] = s * sigm(s);
    }
    __syncthreads();

    float part = 0.f;
    #pragma unroll
    for (int it = 0; it < 3; ++it) {
        const float v = zc[DIM_MEMT + tid + it * 256];
        part = fmaf(v, v, part);
    }
    const float qss = blockReduceSum256(part, red);
    const float qrs = rsqrtf(qss / (float)DIM_Q + 1e-6f);
    #pragma unroll
    for (int it = 0; it < 3; ++it) {
        const int c = tid + it * 256;
        qbuf[(size_t)tok * DIM_Q + c] = zc[DIM_MEMT + c] * qrs * wq[c];
    }

    const int wave = tid >> 6, lane = tid & 63;
    for (int k = wave; k < KK; k += 4) {
        const float v = zc[k * HH + lane];
        float ss = v * v;
        #pragma unroll
        for (int off = 32; off > 0; off >>= 1) ss += __shfl_xor(ss, off);
        const float rs = rsqrtf(ss / (float)HH + 1e-6f);
        const float kval = v * rs * wk[lane];

        const float sraw = zc[DIM_MEM + k];
        float lin = fmaf(dt_scale[k], sraw, dt_bias[k]);
        lin = fminf(fmaxf(lin, -20.f), 20.f);
        float dt = softplusf(lin);
        dt = fminf(fmaxf(dt, 0.001f), 0.1f);
        float Ad = -expf(log_A[k]) * dt;
        Ad = fminf(fmaxf(Ad, -20.f), 0.f);
        const float dec = expf(Ad);

        const float theta = 0.001f + (3.0f - 0.001f) * sigm(theta_raw[k * HH + lane]);
        const float ks = kval * phase_scale[k];
        const float phi = ks / (1.0f + fabsf(ks)) * theta;
        const float kvw = kval * dt;
        float sphi, cphi;
        sincosf(phi, &sphi, &cphi);

        const size_t base = (((size_t)(b * KK + k)) * LL + t) * 128;
        stack[base + lane] = kvw * cphi;
        stack[base + 64 + lane] = kvw * sphi;
        if (lane == 0) decay[((size_t)(b * KK + k)) * LL + t] = dec;
    }
}

// ---------------- scan phase A ----------------
__launch_bounds__(128)
__global__ void scan_a(float* __restrict__ stack, const float* __restrict__ decay,
                       float* __restrict__ pcum, float* __restrict__ cend,
                       float* __restrict__ cp) {
    const int bk = blockIdx.x / NCHUNK;
    const int chunk = blockIdx.x % NCHUNK;
    const int c = threadIdx.x;
    const size_t rowbase = (size_t)bk * LL + chunk * LCHUNK;
    float acc = 0.f, P = 1.f;
    #pragma unroll 4
    for (int tt = 0; tt < LCHUNK; ++tt) {
        const size_t r = rowbase + tt;
        const float d = decay[r];
        const float x = stack[r * 128 + c];
        acc = fmaf(d, acc, x);
        P *= d;
        stack[r * 128 + c] = acc;
        if (c == 0) pcum[r] = P;
    }
    cend[(size_t)blockIdx.x * 128 + c] = acc;
    if (c == 0) cp[blockIdx.x] = P;
}

// ---------------- scan phase B ----------------
__launch_bounds__(128)
__global__ void scan_b(const float* __restrict__ cend, const float* __restrict__ cp,
                       float* __restrict__ carry) {
    const int bk = blockIdx.x;
    const int c = threadIdx.x;
    float cur = 0.f;
    for (int ch = 0; ch < NCHUNK; ++ch) {
        const size_t idx = (size_t)bk * NCHUNK + ch;
        carry[idx * 128 + c] = cur;
        cur = fmaf(cp[idx], cur, cend[idx * 128 + c]);
    }
}

// ---------------- combine: scan fixup, q-match, gate matvec, rms -> OCN bf16 + cskip bf16 ----------------
__launch_bounds__(256)
__global__ void combine_kernel(const float* __restrict__ stack, const float* __restrict__ pcum,
                               const float* __restrict__ carry, const float* __restrict__ qbuf,
                               const float* __restrict__ Z, const float* __restrict__ w_int_raw,
                               const float* __restrict__ W_gate, const float* __restrict__ gn_weight,
                               ushort_t* __restrict__ ocnB, ushort_t* __restrict__ cskB) {
    __shared__ float g_sh[KK * 2 * HH];
    __shared__ float gl[KK];
    __shared__ float red[8];
    const int tok = blockIdx.x;
    const int b = tok / LL, t = tok % LL;
    const int tid = threadIdx.x;
    const int chunk = t / LCHUNK;

    if (tid < KK) gl[tid] = Z[(size_t)tok * DIM_TOTAL + DIM_CONV + DIM_SKIP + tid];
    __syncthreads();

    float part = 0.f;
    #pragma unroll
    for (int it = 0; it < 3; ++it) {
        const int p = tid + it * 256;
        const int k = p >> 6, h = p & 63;
        const int kq = k >> 1;
        const size_t bkL = (size_t)(b * KK + k) * LL + t;
        const size_t base = bkL * 128;
        const float pc = pcum[bkL];
        const size_t cbase = ((size_t)(b * KK + k) * NCHUNK + chunk) * 128;
        const float re = fmaf(pc, carry[cbase + h], stack[base + h]);
        const float im = fmaf(pc, carry[cbase + 64 + h], stack[base + 64 + h]);
        const float2 q2 = *reinterpret_cast<const float2*>(&qbuf[(size_t)tok * DIM_Q + kq * 128 + 2 * h]);
        float wr = w_int_raw[k * HH + h];
        wr = fminf(fmaxf(wr, -5.f), 5.f);
        const float wint = expf(wr);
        const float ore = (re * q2.x + im * q2.y) * wint;
        const float oim = (im * q2.x - re * q2.y) * wint;
        float gr = 0.f, gi = 0.f;
        const int cre = k * 128 + h, cim = k * 128 + 64 + h;
        #pragma unroll
        for (int i = 0; i < KK; ++i) {
            gr = fmaf(gl[i], W_gate[i * (KK * 2 * HH) + cre], gr);
            gi = fmaf(gl[i], W_gate[i * (KK * 2 * HH) + cim], gi);
        }
        const float g_re = ore * sigm(gr);
        const float g_im = oim * sigm(gi);
        g_sh[cre] = g_re;
        g_sh[cim] = g_im;
        part = fmaf(g_re, g_re, part);
        part = fmaf(g_im, g_im, part);
    }
    const float ss = blockReduceSum256(part, red);
    const float rs = rsqrtf(ss / (float)(KK * 2 * HH) + 1e-6f);
    // cskip slice of Z -> bf16 (for gemm2 A operand, K1 segment)
    if (tid < DIM_SKIP)
        cskB[(size_t)tok * DIM_SKIP + tid] = f2bf(Z[(size_t)tok * DIM_TOTAL + DIM_CONV + tid]);
    __syncthreads();
    #pragma unroll
    for (int it = 0; it < 6; ++it) {
        const int c = tid + it * 256;
        ocnB[(size_t)tok * (KK * 2 * HH) + c] = f2bf(g_sh[c] * rs * gn_weight[c]);
    }
}

// ---------------- launch ----------------
static inline size_t pass_need_bytes(int TP) {
    const size_t BP = (size_t)TP / LL;
    size_t total = 0;
    total += (size_t)TP * DIM_TOTAL * 4;        // Z
    total += (size_t)TP * 1536 * 4;             // stack (also: W_inT, then Y bf16)
    total += (size_t)TP * 768 * 4;              // qbuf  (also: xb bf16, then WoutT/Btv/Btg)
    total += (size_t)TP * 12 * 4;               // decay
    total += (size_t)TP * 12 * 4;               // pcum
    total += BP * 12 * NCHUNK * 128 * 4;        // cend
    total += BP * 12 * NCHUNK * 4;              // cp
    total += BP * 12 * NCHUNK * 128 * 4;        // carry
    total += (size_t)TP * 1536 * 4;             // ocn region (bf16 ocn + bf16 cskip)
    return total;
}

extern "C" void kernel_launch(void* const* d_in, const int* in_sizes, int n_in,
                              void* d_out, int out_size, void* d_ws, size_t ws_size,
                              hipStream_t stream) {
    const float* x           = (const float*)d_in[0];
    const float* W_in        = (const float*)d_in[1];
    const float* conv_w      = (const float*)d_in[2];
    const float* wk          = (const float*)d_in[3];
    const float* wq          = (const float*)d_in[4];
    const float* theta_raw   = (const float*)d_in[5];
    const float* w_int_raw   = (const float*)d_in[6];
    const float* dt_scale    = (const float*)d_in[7];
    const float* dt_bias     = (const float*)d_in[8];
    const float* log_A       = (const float*)d_in[9];
    const float* phase_scale = (const float*)d_in[10];
    const float* W_gate      = (const float*)d_in[11];
    const float* gn_weight   = (const float*)d_in[12];
    const float* W_readout   = (const float*)d_in[13];
    const float* W_skip      = (const float*)d_in[14];
    const float* W_out       = (const float*)d_in[15];
    float* out = (float*)d_out;

    int passes = 4;
    if (ws_size >= pass_need_bytes(TTOK))        passes = 1;
    else if (ws_size >= pass_need_bytes(TTOK/2)) passes = 2;

    const int BP = BB / passes;
    const int TP = BP * LL;

    char* wsb = (char*)d_ws;
    const size_t zB     = (size_t)TP * DIM_TOTAL * 4;
    const size_t stackB = (size_t)TP * 1536 * 4;
    const size_t qB     = (size_t)TP * 768 * 4;
    const size_t dB     = (size_t)TP * 12 * 4;
    const size_t cendB  = (size_t)BP * 12 * NCHUNK * 128 * 4;
    const size_t cpB    = (size_t)BP * 12 * NCHUNK * 4;

    float* Z       = (float*)(wsb);
    float* stack   = (float*)(wsb + zB);
    float* qbuf    = (float*)(wsb + zB + stackB);
    float* decay   = (float*)(wsb + zB + stackB + qB);
    float* pcum    = (float*)(wsb + zB + stackB + qB + dB);
    float* cend    = (float*)(wsb + zB + stackB + qB + 2 * dB);
    float* cp      = (float*)(wsb + zB + stackB + qB + 2 * dB + cendB);
    float* carry   = (float*)(wsb + zB + stackB + qB + 2 * dB + cendB + cpB);
    char*  ocnRgn  = (char*)(wsb + zB + stackB + qB + 2 * dB + 2 * cendB + cpB);
    // aliases (dead-region reuse; footprint unchanged):
    ushort_t* xb    = (ushort_t*)qbuf;                    // [TP][768] bf16, dead before feat writes qbuf
    ushort_t* WinT  = (ushort_t*)stack;                   // [1792][768] bf16, dead after GEMM1
    ushort_t* WoutT = (ushort_t*)qbuf;                    // [768][2304] bf16 (3.5 MB), after combine
    ushort_t* Btv   = (ushort_t*)((char*)qbuf + 4 * 1024 * 1024);   // [12][192][320] bf16 (3 MB)
    ushort_t* Btg   = (ushort_t*)((char*)qbuf + 7 * 1024 * 1024);   // [12][192][320] bf16 (3 MB)
    ushort_t* Y     = (ushort_t*)stack;                   // [TP][2304] bf16, after combine
    ushort_t* ocnB  = (ushort_t*)ocnRgn;                  // [TP][1536] bf16
    ushort_t* cskB  = (ushort_t*)(ocnRgn + (size_t)TP * 1536 * 2);  // [TP][192] bf16

    for (int pass = 0; pass < passes; ++pass) {
        const float* xp = x   + (size_t)pass * TP * DD;
        float*       op = out + (size_t)pass * TP * DD;

        // prep: cast x, transpose+cast W_in
        cast_bf16<<<1024, 256, 0, stream>>>(xp, xb, TP * DD / 4);
        transpose_cast<<<dim3(N1PAD / 32, DD / 32), dim3(32, 8), 0, stream>>>(
            W_in, WinT, DD, N1REAL, N1PAD);

        // 1. Z = x @ W_in  (bf16 MFMA)
        mfma_gemm<<<dim3(TP / 128, N1PAD / 128), 256, 0, stream>>>(xb, WinT, Z, N1REAL, DD);

        // 2. conv + features
        feat_kernel<<<TP, 256, 0, stream>>>(Z, conv_w, wk, wq, theta_raw, dt_scale,
                                            dt_bias, log_A, phase_scale, stack, decay, qbuf);

        // 3-4. chunked scan
        scan_a<<<BP * KK * NCHUNK, 128, 0, stream>>>(stack, decay, pcum, cend, cp);
        scan_b<<<BP * KK, 128, 0, stream>>>(cend, cp, carry);

        // 5. combine -> ocn bf16 + cskip bf16
        combine_kernel<<<TP, 256, 0, stream>>>(stack, pcum, carry, qbuf, Z, w_int_raw,
                                               W_gate, gn_weight, ocnB, cskB);

        // prep (qbuf now dead): WoutT, Btv/Btg
        transpose_cast<<<dim3(DD / 32, (KK * 3 * HH) / 32), dim3(32, 8), 0, stream>>>(
            W_out, WoutT, KK * 3 * HH, DD, DD);
        prep_bt<<<dim3(KK, 192), 320, 0, stream>>>(W_readout, W_skip, Btv, Btg);

        // 6. Y(bf16) = val*silu(gate) of grouped MFMA GEMM (readout + skip fused, K=320)
        gemm2_mfma<<<dim3(TP / 128, 3, KK), 256, 0, stream>>>(ocnB, cskB, Btv, Btg, Y);

        // 7. out = Y @ W_out  (bf16 MFMA)
        mfma_gemm<<<dim3(TP / 128, DD / 128), 256, 0, stream>>>(Y, WoutT, op, DD, KK * 3 * HH);
    }
}

// Round 6
// 539.718 us; speedup vs baseline: 4.3855x; 1.2076x over previous
//
#include <hip/hip_runtime.h>
#include <hip/hip_bf16.h>
#include <cstdint>
#include <cstddef>

// ---------------- problem constants ----------------
#define BB 4
#define LL 4096
#define DD 768
#define KK 12
#define HH 64
#define KSZ 4
#define DIM_MEM 768
#define DIM_MEMT 780
#define DIM_Q 768
#define DIM_CONV 1548
#define DIM_SKIP 192
#define DIM_SWH 384
#define DIM_TOTAL 1752
#define TTOK (BB*LL)
#define NCHUNK 128
#define LCHUNK 32            // LL / NCHUNK
#define N1REAL 1752
#define N1PAD 1792

typedef unsigned short ushort_t;
typedef __attribute__((ext_vector_type(8))) short short8v;   // 8 x bf16 (4 VGPRs)
typedef __attribute__((ext_vector_type(4))) float f32x4;

// ---------------- helpers ----------------
__device__ __forceinline__ float sigm(float x) { return 1.0f / (1.0f + expf(-x)); }
__device__ __forceinline__ float softplusf(float x) {
    return (x > 0.f) ? (x + log1pf(expf(-x))) : log1pf(expf(x));
}
__device__ __forceinline__ ushort_t f2bf(float f) {
    __hip_bfloat16 h = __float2bfloat16(f);
    return __builtin_bit_cast(ushort_t, h);
}
__device__ __forceinline__ float bf2f(ushort_t u) {
    const uint32_t i = ((uint32_t)u) << 16;
    return __builtin_bit_cast(float, i);
}
__device__ __forceinline__ float blockReduceSum256(float v, float* sbuf) {
    #pragma unroll
    for (int off = 32; off > 0; off >>= 1) v += __shfl_xor(v, off);
    const int wid = threadIdx.x >> 6;
    __syncthreads();
    if ((threadIdx.x & 63) == 0) sbuf[wid] = v;
    __syncthreads();
    return sbuf[0] + sbuf[1] + sbuf[2] + sbuf[3];
}
__device__ __forceinline__ void gload_lds16(const void* g, void* l) {
    __builtin_amdgcn_global_load_lds(
        (const __attribute__((address_space(1))) void*)g,
        (__attribute__((address_space(3))) void*)l, 16, 0, 0);
}

// ---------------- cast fp32 -> bf16 (vectorized) ----------------
__launch_bounds__(256)
__global__ void cast_bf16(const float* __restrict__ in, ushort_t* __restrict__ out, int n4) {
    const int stride = gridDim.x * 256;
    for (int i = blockIdx.x * 256 + threadIdx.x; i < n4; i += stride) {
        const float4 v = reinterpret_cast<const float4*>(in)[i];
        ushort4 o;
        o.x = f2bf(v.x); o.y = f2bf(v.y); o.z = f2bf(v.z); o.w = f2bf(v.w);
        reinterpret_cast<ushort4*>(out)[i] = o;
    }
}

// ---------------- transpose + cast: in[R][Cc] f32 -> out[Cpad][R] bf16 (zero pad) ----------------
__global__ void transpose_cast(const float* __restrict__ in, ushort_t* __restrict__ out,
                               int R, int Cc, int Cpad) {
    __shared__ float tile[32][33];
    const int tx = threadIdx.x, ty = threadIdx.y;
    const int c0 = blockIdx.x * 32, r0 = blockIdx.y * 32;
    #pragma unroll
    for (int rr = ty; rr < 32; rr += 8) {
        const int r = r0 + rr, c = c0 + tx;
        tile[rr][tx] = (r < R && c < Cc) ? in[(size_t)r * Cc + c] : 0.f;
    }
    __syncthreads();
    #pragma unroll
    for (int rr = ty; rr < 32; rr += 8) {
        const int c = c0 + rr, r = r0 + tx;
        if (c < Cpad && r < R)
            out[(size_t)c * R + r] = f2bf(tile[tx][rr]);
    }
}

// ---------------- build Bt for gemm2: Btv/Btg [12][192][320] bf16 ----------------
__global__ void prep_bt(const float* __restrict__ Wr, const float* __restrict__ Wskip,
                        ushort_t* __restrict__ Btv, ushort_t* __restrict__ Btg) {
    const int k = blockIdx.x, n = blockIdx.y, kk = threadIdx.x;   // block 320
    float v, g;
    if (kk < 128) {
        const size_t base = ((size_t)k * 128 + kk) * DIM_SWH;
        v = Wr[base + n];
        g = Wr[base + 192 + n];
    } else {
        const size_t base = (size_t)(kk - 128) * (KK * DIM_SWH) + (size_t)k * DIM_SWH;
        v = Wskip[base + n];
        g = Wskip[base + 192 + n];
    }
    const size_t o = ((size_t)k * 192 + n) * 320 + kk;
    Btv[o] = f2bf(v);
    Btg[o] = f2bf(g);
}

// ---------------- bf16 MFMA GEMM: C[M,Nreal] = A[M,K]bf16 @ Bt[Npad,K]bf16^T ----------------
// C dtype: bf16 if BF16OUT else f32.
template <bool BF16OUT>
__launch_bounds__(256)
__global__ void mfma_gemm(const ushort_t* __restrict__ A, const ushort_t* __restrict__ Bt,
                          void* __restrict__ Cv, int Nreal, int K) {
    __shared__ ushort_t As[2][128 * 64];
    __shared__ ushort_t Bs[2][128 * 64];
    const int tid = threadIdx.x;
    const int lane = tid & 63, w = tid >> 6;
    const int m0 = blockIdx.x * 128, n0 = blockIdx.y * 128;
    const int wm = w & 1, wn = w >> 1;
    const int nkt = K >> 6;
    const int lrow = lane >> 3;
    const int lcol = (lane & 7) * 8;

    f32x4 acc[4][4] = {};

    auto stage = [&](int buf, int k0) {
        #pragma unroll
        for (int i = 0; i < 4; ++i) {
            const int seg = w * 4 + i;
            const int row = seg * 8 + lrow;
            gload_lds16(&A[(size_t)(m0 + row) * K + k0 + lcol], &As[buf][seg * 512]);
            gload_lds16(&Bt[(size_t)(n0 + row) * K + k0 + lcol], &Bs[buf][seg * 512]);
        }
    };

    stage(0, 0);
    for (int kt = 0; kt < nkt; ++kt) {
        const int cur = kt & 1;
        __syncthreads();
        if (kt + 1 < nkt) stage(cur ^ 1, (kt + 1) << 6);
        #pragma unroll
        for (int kk = 0; kk < 2; ++kk) {
            short8v a[4], b[4];
            #pragma unroll
            for (int i = 0; i < 4; ++i)
                a[i] = *(const short8v*)&As[cur][(wm * 64 + i * 16 + (lane & 15)) * 64 + kk * 32 + (lane >> 4) * 8];
            #pragma unroll
            for (int j = 0; j < 4; ++j)
                b[j] = *(const short8v*)&Bs[cur][(wn * 64 + j * 16 + (lane & 15)) * 64 + kk * 32 + (lane >> 4) * 8];
            #pragma unroll
            for (int i = 0; i < 4; ++i)
                #pragma unroll
                for (int j = 0; j < 4; ++j)
                    acc[i][j] = __builtin_amdgcn_mfma_f32_16x16x32_bf16(a[i], b[j], acc[i][j], 0, 0, 0);
        }
    }
    #pragma unroll
    for (int i = 0; i < 4; ++i) {
        const int rbase = m0 + wm * 64 + i * 16 + (lane >> 4) * 4;
        #pragma unroll
        for (int j = 0; j < 4; ++j) {
            const int col = n0 + wn * 64 + j * 16 + (lane & 15);
            if (col < Nreal) {
                #pragma unroll
                for (int r = 0; r < 4; ++r) {
                    if constexpr (BF16OUT)
                        ((ushort_t*)Cv)[(size_t)(rbase + r) * Nreal + col] = f2bf(acc[i][j][r]);
                    else
                        ((float*)Cv)[(size_t)(rbase + r) * Nreal + col] = acc[i][j][r];
                }
            }
        }
    }
}

// ---------------- gemm2 MFMA: per-k grouped GEMM with fused val*silu(gate) ----------------
__launch_bounds__(256)
__global__ void gemm2_mfma(const ushort_t* __restrict__ OCNb, const ushort_t* __restrict__ CskB,
                           const ushort_t* __restrict__ Btv, const ushort_t* __restrict__ Btg,
                           ushort_t* __restrict__ Y) {
    __shared__ ushort_t As[2][128 * 64];
    __shared__ ushort_t Bvs[2][64 * 64];
    __shared__ ushort_t Bgs[2][64 * 64];
    const int tid = threadIdx.x;
    const int lane = tid & 63, w = tid >> 6;
    const int m0 = blockIdx.x * 128;
    const int n0 = blockIdx.y * 64;
    const int k  = blockIdx.z;
    const int wm = w & 1, wn = w >> 1;
    const int lrow = lane >> 3;
    const int lcol = (lane & 7) * 8;
    const ushort_t* btv = Btv + (size_t)k * 192 * 320;
    const ushort_t* btg = Btg + (size_t)k * 192 * 320;

    f32x4 accV[4][2] = {};
    f32x4 accG[4][2] = {};

    auto stage = [&](int buf, int kt) {
        #pragma unroll
        for (int i = 0; i < 4; ++i) {
            const int seg = w * 4 + i;
            const int row = seg * 8 + lrow;
            const ushort_t* src = (kt < 2)
                ? OCNb + (size_t)(m0 + row) * (KK * 2 * HH) + k * 128 + kt * 64 + lcol
                : CskB + (size_t)(m0 + row) * DIM_SKIP + (kt - 2) * 64 + lcol;
            gload_lds16(src, &As[buf][seg * 512]);
        }
        #pragma unroll
        for (int i = 0; i < 2; ++i) {
            const int seg = w * 2 + i;
            const int row = seg * 8 + lrow;
            gload_lds16(btv + (size_t)(n0 + row) * 320 + kt * 64 + lcol, &Bvs[buf][seg * 512]);
            gload_lds16(btg + (size_t)(n0 + row) * 320 + kt * 64 + lcol, &Bgs[buf][seg * 512]);
        }
    };

    stage(0, 0);
    for (int kt = 0; kt < 5; ++kt) {
        const int cur = kt & 1;
        __syncthreads();
        if (kt + 1 < 5) stage(cur ^ 1, kt + 1);
        #pragma unroll
        for (int kk = 0; kk < 2; ++kk) {
            short8v a[4], bv[2], bg[2];
            #pragma unroll
            for (int i = 0; i < 4; ++i)
                a[i] = *(const short8v*)&As[cur][(wm * 64 + i * 16 + (lane & 15)) * 64 + kk * 32 + (lane >> 4) * 8];
            #pragma unroll
            for (int j = 0; j < 2; ++j) {
                bv[j] = *(const short8v*)&Bvs[cur][(wn * 32 + j * 16 + (lane & 15)) * 64 + kk * 32 + (lane >> 4) * 8];
                bg[j] = *(const short8v*)&Bgs[cur][(wn * 32 + j * 16 + (lane & 15)) * 64 + kk * 32 + (lane >> 4) * 8];
            }
            #pragma unroll
            for (int i = 0; i < 4; ++i)
                #pragma unroll
                for (int j = 0; j < 2; ++j) {
                    accV[i][j] = __builtin_amdgcn_mfma_f32_16x16x32_bf16(a[i], bv[j], accV[i][j], 0, 0, 0);
                    accG[i][j] = __builtin_amdgcn_mfma_f32_16x16x32_bf16(a[i], bg[j], accG[i][j], 0, 0, 0);
                }
        }
    }
    #pragma unroll
    for (int i = 0; i < 4; ++i) {
        const int rbase = m0 + wm * 64 + i * 16 + (lane >> 4) * 4;
        #pragma unroll
        for (int j = 0; j < 2; ++j) {
            const int col = k * 192 + n0 + wn * 32 + j * 16 + (lane & 15);
            #pragma unroll
            for (int r = 0; r < 4; ++r) {
                const float g = accG[i][j][r];
                Y[(size_t)(rbase + r) * (KK * 3 * HH) + col] = f2bf(accV[i][j][r] * (g * sigm(g)));
            }
        }
    }
}

// ---------------- fused feature + scan: per (b,k,chunk32), 64 lanes = 64 heads ----------------
// conv(4-tap ring) + silu + rms(wave) + dt/decay + phase trig + in-register scan.
// acc layout: [(b*12+k)*LL + t][64] float2 {re,im}.
__launch_bounds__(64)
__global__ void feat_scan(const ushort_t* __restrict__ Zb, const float* __restrict__ conv_w,
                          const float* __restrict__ wk, const float* __restrict__ theta_raw,
                          const float* __restrict__ dt_scale, const float* __restrict__ dt_bias,
                          const float* __restrict__ log_A, const float* __restrict__ phase_scale,
                          float2* __restrict__ acc, float* __restrict__ pcum,
                          float2* __restrict__ cend, float* __restrict__ cp) {
    const int blk = blockIdx.x;                  // (b*KK+k)*NCHUNK + chunk
    const int bk = blk / NCHUNK, chunk = blk - bk * NCHUNK;
    const int b = bk / KK, k = bk - b * KK;
    const int h = threadIdx.x;
    const int t0 = chunk * LCHUNK;
    const int cm_ch = k * HH + h;
    const int cs_ch = DIM_MEM + k;

    const float w0 = conv_w[0 * DIM_CONV + cm_ch];
    const float w1 = conv_w[1 * DIM_CONV + cm_ch];
    const float w2 = conv_w[2 * DIM_CONV + cm_ch];
    const float w3 = conv_w[3 * DIM_CONV + cm_ch];
    const float s0 = conv_w[0 * DIM_CONV + cs_ch];
    const float s1 = conv_w[1 * DIM_CONV + cs_ch];
    const float s2 = conv_w[2 * DIM_CONV + cs_ch];
    const float s3 = conv_w[3 * DIM_CONV + cs_ch];
    const float wkh = wk[h];
    const float th = 0.001f + (3.0f - 0.001f) * sigm(theta_raw[cm_ch]);
    const float ps = phase_scale[k];
    const float dts = dt_scale[k], dtb = dt_bias[k];
    const float eA = expf(log_A[k]);

    const size_t rowb = (size_t)b * LL;
    auto zm_at = [&](int t) -> float {
        return (t >= 0) ? bf2f(Zb[(rowb + t) * DIM_TOTAL + cm_ch]) : 0.f;
    };
    auto zs_at = [&](int t) -> float {
        return (t >= 0) ? bf2f(Zb[(rowb + t) * DIM_TOTAL + cs_ch]) : 0.f;
    };
    float zm3 = zm_at(t0 - 3), zm2 = zm_at(t0 - 2), zm1 = zm_at(t0 - 1);
    float zs3 = zs_at(t0 - 3), zs2 = zs_at(t0 - 2), zs1 = zs_at(t0 - 1);

    float are = 0.f, aim = 0.f, P = 1.f;
    for (int tt = 0; tt < LCHUNK; ++tt) {
        const int t = t0 + tt;
        const float zm0 = bf2f(Zb[(rowb + t) * DIM_TOTAL + cm_ch]);
        const float zs0 = bf2f(Zb[(rowb + t) * DIM_TOTAL + cs_ch]);
        float cm = fmaf(w0, zm3, fmaf(w1, zm2, fmaf(w2, zm1, w3 * zm0)));
        float cs = fmaf(s0, zs3, fmaf(s1, zs2, fmaf(s2, zs1, s3 * zs0)));
        const float um = cm * sigm(cm);       // silu -> mem channel value
        const float us = cs * sigm(cs);       // silu -> s_raw value
        float ssq = um * um;
        #pragma unroll
        for (int off = 32; off > 0; off >>= 1) ssq += __shfl_xor(ssq, off);
        const float kval = um * rsqrtf(ssq * (1.0f / (float)HH) + 1e-6f) * wkh;
        float lin = fminf(fmaxf(fmaf(dts, us, dtb), -20.f), 20.f);
        float dt = fminf(fmaxf(softplusf(lin), 0.001f), 0.1f);
        const float Ad = fminf(fmaxf(-eA * dt, -20.f), 0.f);
        const float dec = expf(Ad);
        const float ks = kval * ps;
        const float phi = ks / (1.0f + fabsf(ks)) * th;
        const float kvw = kval * dt;
        float sp, cq;
        sincosf(phi, &sp, &cq);
        are = fmaf(dec, are, kvw * cq);
        aim = fmaf(dec, aim, kvw * sp);
        P *= dec;
        acc[((size_t)bk * LL + t) * HH + h] = make_float2(are, aim);
        if (h == 0) pcum[(size_t)bk * LL + t] = P;
        zm3 = zm2; zm2 = zm1; zm1 = zm0;
        zs3 = zs2; zs2 = zs1; zs1 = zs0;
    }
    cend[(size_t)blk * HH + h] = make_float2(are, aim);
    if (h == 0) cp[blk] = P;
}

// ---------------- scan phase B: carry propagation across chunks ----------------
__launch_bounds__(128)
__global__ void scan_b(const float* __restrict__ cend, const float* __restrict__ cp,
                       float* __restrict__ carry) {
    const int bk = blockIdx.x;
    const int c = threadIdx.x;           // 0..127 (float view of float2[64])
    float cur = 0.f;
    for (int ch = 0; ch < NCHUNK; ++ch) {
        const size_t idx = (size_t)bk * NCHUNK + ch;
        carry[idx * 128 + c] = cur;
        cur = fmaf(cp[idx], cur, cend[idx * 128 + c]);
    }
}

// ---------------- combine: inline q(conv+rms), scan fixup, q-match, gate, rms -> ocn/cskip bf16 ----------------
__launch_bounds__(256)
__global__ void combine_kernel(const float2* __restrict__ acc, const float* __restrict__ pcum,
                               const float2* __restrict__ carry, const ushort_t* __restrict__ Zb,
                               const float* __restrict__ conv_w, const float* __restrict__ wq,
                               const float* __restrict__ w_int_raw, const float* __restrict__ W_gate,
                               const float* __restrict__ gn_weight,
                               ushort_t* __restrict__ ocnB, ushort_t* __restrict__ cskB) {
    __shared__ float q_sh[DIM_Q];
    __shared__ float g_sh[KK * 2 * HH];
    __shared__ float gl[KK];
    __shared__ float red[8];
    const int tok = blockIdx.x;
    const int b = tok / LL, t = tok % LL;
    const int tid = threadIdx.x;
    const int chunk = t / LCHUNK;
    const size_t zrow = (size_t)tok * DIM_TOTAL;

    if (tid < KK) gl[tid] = bf2f(Zb[zrow + DIM_CONV + DIM_SKIP + tid]);
    if (tid < DIM_SKIP) cskB[(size_t)tok * DIM_SKIP + tid] = Zb[zrow + DIM_CONV + tid];

    // q = rms(silu(conv(q_raw)), 768) * wq  — inline conv from bf16 Z
    float part = 0.f;
    float qv[3];
    #pragma unroll
    for (int it = 0; it < 3; ++it) {
        const int c = tid + it * 256;
        const int ch = DIM_MEMT + c;
        float s = 0.f;
        #pragma unroll
        for (int j = 0; j < KSZ; ++j) {
            const int tt2 = t + j - (KSZ - 1);
            if (tt2 >= 0)
                s = fmaf(conv_w[j * DIM_CONV + ch],
                         bf2f(Zb[((size_t)(b * LL + tt2)) * DIM_TOTAL + ch]), s);
        }
        const float u = s * sigm(s);
        qv[it] = u;
        part = fmaf(u, u, part);
    }
    const float qss = blockReduceSum256(part, red);
    const float qrs = rsqrtf(qss / (float)DIM_Q + 1e-6f);
    #pragma unroll
    for (int it = 0; it < 3; ++it) {
        const int c = tid + it * 256;
        q_sh[c] = qv[it] * qrs * wq[c];
    }
    __syncthreads();

    float part2 = 0.f;
    #pragma unroll
    for (int it = 0; it < 3; ++it) {
        const int p = tid + it * 256;
        const int k = p >> 6, h = p & 63;
        const int kq = k >> 1;
        const size_t bkL = (size_t)(b * KK + k) * LL + t;
        const float pc = pcum[bkL];
        const float2 a2 = acc[bkL * HH + h];
        const float2 c2 = carry[((size_t)(b * KK + k) * NCHUNK + chunk) * HH + h];
        const float re = fmaf(pc, c2.x, a2.x);
        const float im = fmaf(pc, c2.y, a2.y);
        const float qre = q_sh[kq * 128 + 2 * h];
        const float qim = q_sh[kq * 128 + 2 * h + 1];
        float wr = w_int_raw[k * HH + h];
        wr = fminf(fmaxf(wr, -5.f), 5.f);
        const float wint = expf(wr);
        const float ore = (re * qre + im * qim) * wint;
        const float oim = (im * qre - re * qim) * wint;
        float gr = 0.f, gi = 0.f;
        const int cre = k * 128 + h, cim = k * 128 + 64 + h;
        #pragma unroll
        for (int i = 0; i < KK; ++i) {
            gr = fmaf(gl[i], W_gate[i * (KK * 2 * HH) + cre], gr);
            gi = fmaf(gl[i], W_gate[i * (KK * 2 * HH) + cim], gi);
        }
        const float g_re = ore * sigm(gr);
        const float g_im = oim * sigm(gi);
        g_sh[cre] = g_re;
        g_sh[cim] = g_im;
        part2 = fmaf(g_re, g_re, part2);
        part2 = fmaf(g_im, g_im, part2);
    }
    const float ss = blockReduceSum256(part2, red);
    const float rs = rsqrtf(ss / (float)(KK * 2 * HH) + 1e-6f);
    __syncthreads();
    #pragma unroll
    for (int it = 0; it < 6; ++it) {
        const int c = tid + it * 256;
        ocnB[(size_t)tok * (KK * 2 * HH) + c] = f2bf(g_sh[c] * rs * gn_weight[c]);
    }
}

// ---------------- launch ----------------
static inline size_t pass_need_bytes(int TP) {
    const size_t BP = (size_t)TP / LL;
    size_t total = 0;
    total += (size_t)TP * DIM_TOTAL * 2;            // Zb bf16
    total += (size_t)TP * KK * HH * 8;              // acc f32x2 (aliases WinT, then Y)
    total += (size_t)TP * KK * 4;                   // pcum
    total += BP * KK * NCHUNK * HH * 8;             // cend
    total += BP * KK * NCHUNK * 4;                  // cp
    total += BP * KK * NCHUNK * HH * 8;             // carry
    total += (size_t)TP * (KK * 2 * HH + DIM_SKIP) * 2; // ocnB + cskB (aliases xb)
    total += 8ull * 1024 * 1024;                    // WoutT + Btv + Btg
    return total;
}

extern "C" void kernel_launch(void* const* d_in, const int* in_sizes, int n_in,
                              void* d_out, int out_size, void* d_ws, size_t ws_size,
                              hipStream_t stream) {
    const float* x           = (const float*)d_in[0];
    const float* W_in        = (const float*)d_in[1];
    const float* conv_w      = (const float*)d_in[2];
    const float* wk          = (const float*)d_in[3];
    const float* wq          = (const float*)d_in[4];
    const float* theta_raw   = (const float*)d_in[5];
    const float* w_int_raw   = (const float*)d_in[6];
    const float* dt_scale    = (const float*)d_in[7];
    const float* dt_bias     = (const float*)d_in[8];
    const float* log_A       = (const float*)d_in[9];
    const float* phase_scale = (const float*)d_in[10];
    const float* W_gate      = (const float*)d_in[11];
    const float* gn_weight   = (const float*)d_in[12];
    const float* W_readout   = (const float*)d_in[13];
    const float* W_skip      = (const float*)d_in[14];
    const float* W_out       = (const float*)d_in[15];
    float* out = (float*)d_out;

    int passes = 4;
    if (ws_size >= pass_need_bytes(TTOK))        passes = 1;
    else if (ws_size >= pass_need_bytes(TTOK/2)) passes = 2;

    const int BP = BB / passes;
    const int TP = BP * LL;

    char* p = (char*)d_ws;
    ushort_t* Zb   = (ushort_t*)p;               p += (size_t)TP * DIM_TOTAL * 2;
    char* accR     = p;
    float2* acc    = (float2*)p;                 p += (size_t)TP * KK * HH * 8;
    float* pcum    = (float*)p;                  p += (size_t)TP * KK * 4;
    float2* cendv  = (float2*)p;                 p += (size_t)BP * KK * NCHUNK * HH * 8;
    float* cp      = (float*)p;                  p += (size_t)BP * KK * NCHUNK * 4;
    float2* carry  = (float2*)p;                 p += (size_t)BP * KK * NCHUNK * HH * 8;
    char* ocnR     = p;
    ushort_t* ocnB = (ushort_t*)p;               p += (size_t)TP * (KK * 2 * HH) * 2;
    ushort_t* cskB = (ushort_t*)p;               p += (size_t)TP * DIM_SKIP * 2;
    ushort_t* WoutT= (ushort_t*)p;               p += (size_t)768 * 2304 * 2;
    ushort_t* Btv  = (ushort_t*)p;               p += (size_t)KK * 192 * 320 * 2;
    ushort_t* Btg  = (ushort_t*)p;               p += (size_t)KK * 192 * 320 * 2;
    // aliases (stream-serial lifetime reuse):
    ushort_t* xb   = (ushort_t*)ocnR;   // [TP][768] bf16, dead after GEMM1 (combine writes ocn later)
    ushort_t* WinT = (ushort_t*)accR;   // [1792][768] bf16, dead after GEMM1 (feat_scan writes acc later)
    ushort_t* Y    = (ushort_t*)accR;   // [TP][2304] bf16 (<= acc bytes), written after combine

    for (int pass = 0; pass < passes; ++pass) {
        const float* xp = x   + (size_t)pass * TP * DD;
        float*       op = out + (size_t)pass * TP * DD;

        // input-only preps (front-loaded)
        cast_bf16<<<1024, 256, 0, stream>>>(xp, xb, TP * DD / 4);
        transpose_cast<<<dim3(N1PAD / 32, DD / 32), dim3(32, 8), 0, stream>>>(
            W_in, WinT, DD, N1REAL, N1PAD);
        transpose_cast<<<dim3(DD / 32, (KK * 3 * HH) / 32), dim3(32, 8), 0, stream>>>(
            W_out, WoutT, KK * 3 * HH, DD, DD);
        prep_bt<<<dim3(KK, 192), 320, 0, stream>>>(W_readout, W_skip, Btv, Btg);

        // 1. Zb = x @ W_in  (bf16 MFMA, bf16 output)
        mfma_gemm<true><<<dim3(TP / 128, N1PAD / 128), 256, 0, stream>>>(xb, WinT, Zb, N1REAL, DD);

        // 2. fused conv+feat+scan (mem path)
        feat_scan<<<BP * KK * NCHUNK, 64, 0, stream>>>(Zb, conv_w, wk, theta_raw, dt_scale,
                                                       dt_bias, log_A, phase_scale,
                                                       acc, pcum, cendv, cp);

        // 3. carry propagation
        scan_b<<<BP * KK, 128, 0, stream>>>((const float*)cendv, cp, (float*)carry);

        // 4. combine (inline q) -> ocn bf16 + cskip bf16
        combine_kernel<<<TP, 256, 0, stream>>>(acc, pcum, carry, Zb, conv_w, wq, w_int_raw,
                                               W_gate, gn_weight, ocnB, cskB);

        // 5. Y(bf16) = val*silu(gate) of grouped MFMA GEMM (readout + skip, K=320)
        gemm2_mfma<<<dim3(TP / 128, 3, KK), 256, 0, stream>>>(ocnB, cskB, Btv, Btg, Y);

        // 6. out = Y @ W_out  (bf16 MFMA, f32 output)
        mfma_gemm<false><<<dim3(TP / 128, DD / 128), 256, 0, stream>>>(Y, WoutT, op, DD, KK * 3 * HH);
    }
}

// Round 7
// 481.256 us; speedup vs baseline: 4.9183x; 1.1215x over previous
//
#include <hip/hip_runtime.h>
#include <hip/hip_bf16.h>
#include <cstdint>
#include <cstddef>

// ---------------- problem constants ----------------
#define BB 4
#define LL 4096
#define DD 768
#define KK 12
#define HH 64
#define KSZ 4
#define DIM_MEM 768
#define DIM_MEMT 780
#define DIM_Q 768
#define DIM_CONV 1548
#define DIM_SKIP 192
#define DIM_SWH 384
#define DIM_TOTAL 1752
#define TTOK (BB*LL)
#define NCHUNK 128
#define LCHUNK 32            // LL / NCHUNK
#define N1REAL 1752
#define N1PAD 1792

typedef unsigned short ushort_t;
typedef __attribute__((ext_vector_type(8))) short short8v;   // 8 x bf16 (4 VGPRs)
typedef __attribute__((ext_vector_type(4))) float f32x4;

// ---------------- helpers ----------------
__device__ __forceinline__ float sigm(float x) { return 1.0f / (1.0f + expf(-x)); }
__device__ __forceinline__ float softplusf(float x) {
    return (x > 0.f) ? (x + log1pf(expf(-x))) : log1pf(expf(x));
}
__device__ __forceinline__ ushort_t f2bf(float f) {
    __hip_bfloat16 h = __float2bfloat16(f);
    return __builtin_bit_cast(ushort_t, h);
}
__device__ __forceinline__ float bf2f(ushort_t u) {
    const uint32_t i = ((uint32_t)u) << 16;
    return __builtin_bit_cast(float, i);
}
__device__ __forceinline__ float blockReduceSum256(float v, float* sbuf) {
    #pragma unroll
    for (int off = 32; off > 0; off >>= 1) v += __shfl_xor(v, off);
    const int wid = threadIdx.x >> 6;
    __syncthreads();
    if ((threadIdx.x & 63) == 0) sbuf[wid] = v;
    __syncthreads();
    return sbuf[0] + sbuf[1] + sbuf[2] + sbuf[3];
}
__device__ __forceinline__ void gload_lds16(const void* g, void* l) {
    __builtin_amdgcn_global_load_lds(
        (const __attribute__((address_space(1))) void*)g,
        (__attribute__((address_space(3))) void*)l, 16, 0, 0);
}

// ---------------- cast fp32 -> bf16 (vectorized) ----------------
__launch_bounds__(256)
__global__ void cast_bf16(const float* __restrict__ in, ushort_t* __restrict__ out, int n4) {
    const int stride = gridDim.x * 256;
    for (int i = blockIdx.x * 256 + threadIdx.x; i < n4; i += stride) {
        const float4 v = reinterpret_cast<const float4*>(in)[i];
        ushort4 o;
        o.x = f2bf(v.x); o.y = f2bf(v.y); o.z = f2bf(v.z); o.w = f2bf(v.w);
        reinterpret_cast<ushort4*>(out)[i] = o;
    }
}

// ---------------- transpose + cast: in[R][Cc] f32 -> out[Cpad][R] bf16 (zero pad) ----------------
__global__ void transpose_cast(const float* __restrict__ in, ushort_t* __restrict__ out,
                               int R, int Cc, int Cpad) {
    __shared__ float tile[32][33];
    const int tx = threadIdx.x, ty = threadIdx.y;
    const int c0 = blockIdx.x * 32, r0 = blockIdx.y * 32;
    #pragma unroll
    for (int rr = ty; rr < 32; rr += 8) {
        const int r = r0 + rr, c = c0 + tx;
        tile[rr][tx] = (r < R && c < Cc) ? in[(size_t)r * Cc + c] : 0.f;
    }
    __syncthreads();
    #pragma unroll
    for (int rr = ty; rr < 32; rr += 8) {
        const int c = c0 + rr, r = r0 + tx;
        if (c < Cpad && r < R)
            out[(size_t)c * R + r] = f2bf(tile[tx][rr]);
    }
}

// ---------------- build Bt for gemm2: Btv/Btg [12][192][320] bf16 ----------------
__global__ void prep_bt(const float* __restrict__ Wr, const float* __restrict__ Wskip,
                        ushort_t* __restrict__ Btv, ushort_t* __restrict__ Btg) {
    const int k = blockIdx.x, n = blockIdx.y, kk = threadIdx.x;   // block 320
    float v, g;
    if (kk < 128) {
        const size_t base = ((size_t)k * 128 + kk) * DIM_SWH;
        v = Wr[base + n];
        g = Wr[base + 192 + n];
    } else {
        const size_t base = (size_t)(kk - 128) * (KK * DIM_SWH) + (size_t)k * DIM_SWH;
        v = Wskip[base + n];
        g = Wskip[base + 192 + n];
    }
    const size_t o = ((size_t)k * 192 + n) * 320 + kk;
    Btv[o] = f2bf(v);
    Btg[o] = f2bf(g);
}

// ---------------- bf16 MFMA GEMM (BK=32, 5 blocks/CU): C[M,Nreal] = A @ Bt^T ----------------
// grid (M/128, Npad/128), block 256 (4 waves). K % 32 == 0. LDS 32 KB total.
// C dtype: bf16 if BF16OUT else f32.
template <bool BF16OUT>
__launch_bounds__(256)
__global__ void mfma_gemm(const ushort_t* __restrict__ A, const ushort_t* __restrict__ Bt,
                          void* __restrict__ Cv, int Nreal, int K) {
    __shared__ ushort_t As[2][128 * 32];
    __shared__ ushort_t Bs[2][128 * 32];
    const int tid = threadIdx.x;
    const int lane = tid & 63, w = tid >> 6;
    const int m0 = blockIdx.x * 128, n0 = blockIdx.y * 128;
    const int wm = w & 1, wn = w >> 1;
    const int nkt = K >> 5;
    const int lrow = lane >> 2;          // 0..15 (row within 16-row seg)
    const int lcol = (lane & 3) * 8;     // 0,8,16,24 (bf16 col)

    f32x4 acc[4][4] = {};

    auto stage = [&](int buf, int k0) {
        #pragma unroll
        for (int i = 0; i < 2; ++i) {
            const int seg = w * 2 + i;               // 0..7 (16 rows each)
            const int row = seg * 16 + lrow;         // 0..127
            gload_lds16(&A[(size_t)(m0 + row) * K + k0 + lcol], &As[buf][seg * 512]);
            gload_lds16(&Bt[(size_t)(n0 + row) * K + k0 + lcol], &Bs[buf][seg * 512]);
        }
    };

    stage(0, 0);
    for (int kt = 0; kt < nkt; ++kt) {
        const int cur = kt & 1;
        __syncthreads();                              // drains stage issued last iter
        if (kt + 1 < nkt) stage(cur ^ 1, (kt + 1) << 5);
        short8v a[4], b[4];
        #pragma unroll
        for (int i = 0; i < 4; ++i)
            a[i] = *(const short8v*)&As[cur][(wm * 64 + i * 16 + (lane & 15)) * 32 + (lane >> 4) * 8];
        #pragma unroll
        for (int j = 0; j < 4; ++j)
            b[j] = *(const short8v*)&Bs[cur][(wn * 64 + j * 16 + (lane & 15)) * 32 + (lane >> 4) * 8];
        #pragma unroll
        for (int i = 0; i < 4; ++i)
            #pragma unroll
            for (int j = 0; j < 4; ++j)
                acc[i][j] = __builtin_amdgcn_mfma_f32_16x16x32_bf16(a[i], b[j], acc[i][j], 0, 0, 0);
    }
    #pragma unroll
    for (int i = 0; i < 4; ++i) {
        const int rbase = m0 + wm * 64 + i * 16 + (lane >> 4) * 4;
        #pragma unroll
        for (int j = 0; j < 4; ++j) {
            const int col = n0 + wn * 64 + j * 16 + (lane & 15);
            if (col < Nreal) {
                #pragma unroll
                for (int r = 0; r < 4; ++r) {
                    if constexpr (BF16OUT)
                        ((ushort_t*)Cv)[(size_t)(rbase + r) * Nreal + col] = f2bf(acc[i][j][r]);
                    else
                        ((float*)Cv)[(size_t)(rbase + r) * Nreal + col] = acc[i][j][r];
                }
            }
        }
    }
}

// ---------------- gemm2 MFMA: per-k grouped GEMM with fused val*silu(gate) ----------------
__launch_bounds__(256)
__global__ void gemm2_mfma(const ushort_t* __restrict__ OCNb, const ushort_t* __restrict__ CskB,
                           const ushort_t* __restrict__ Btv, const ushort_t* __restrict__ Btg,
                           ushort_t* __restrict__ Y) {
    __shared__ ushort_t As[2][128 * 64];
    __shared__ ushort_t Bvs[2][64 * 64];
    __shared__ ushort_t Bgs[2][64 * 64];
    const int tid = threadIdx.x;
    const int lane = tid & 63, w = tid >> 6;
    const int m0 = blockIdx.x * 128;
    const int n0 = blockIdx.y * 64;
    const int k  = blockIdx.z;
    const int wm = w & 1, wn = w >> 1;
    const int lrow = lane >> 3;
    const int lcol = (lane & 7) * 8;
    const ushort_t* btv = Btv + (size_t)k * 192 * 320;
    const ushort_t* btg = Btg + (size_t)k * 192 * 320;

    f32x4 accV[4][2] = {};
    f32x4 accG[4][2] = {};

    auto stage = [&](int buf, int kt) {
        #pragma unroll
        for (int i = 0; i < 4; ++i) {
            const int seg = w * 4 + i;
            const int row = seg * 8 + lrow;
            const ushort_t* src = (kt < 2)
                ? OCNb + (size_t)(m0 + row) * (KK * 2 * HH) + k * 128 + kt * 64 + lcol
                : CskB + (size_t)(m0 + row) * DIM_SKIP + (kt - 2) * 64 + lcol;
            gload_lds16(src, &As[buf][seg * 512]);
        }
        #pragma unroll
        for (int i = 0; i < 2; ++i) {
            const int seg = w * 2 + i;
            const int row = seg * 8 + lrow;
            gload_lds16(btv + (size_t)(n0 + row) * 320 + kt * 64 + lcol, &Bvs[buf][seg * 512]);
            gload_lds16(btg + (size_t)(n0 + row) * 320 + kt * 64 + lcol, &Bgs[buf][seg * 512]);
        }
    };

    stage(0, 0);
    for (int kt = 0; kt < 5; ++kt) {
        const int cur = kt & 1;
        __syncthreads();
        if (kt + 1 < 5) stage(cur ^ 1, kt + 1);
        #pragma unroll
        for (int kk = 0; kk < 2; ++kk) {
            short8v a[4], bv[2], bg[2];
            #pragma unroll
            for (int i = 0; i < 4; ++i)
                a[i] = *(const short8v*)&As[cur][(wm * 64 + i * 16 + (lane & 15)) * 64 + kk * 32 + (lane >> 4) * 8];
            #pragma unroll
            for (int j = 0; j < 2; ++j) {
                bv[j] = *(const short8v*)&Bvs[cur][(wn * 32 + j * 16 + (lane & 15)) * 64 + kk * 32 + (lane >> 4) * 8];
                bg[j] = *(const short8v*)&Bgs[cur][(wn * 32 + j * 16 + (lane & 15)) * 64 + kk * 32 + (lane >> 4) * 8];
            }
            #pragma unroll
            for (int i = 0; i < 4; ++i)
                #pragma unroll
                for (int j = 0; j < 2; ++j) {
                    accV[i][j] = __builtin_amdgcn_mfma_f32_16x16x32_bf16(a[i], bv[j], accV[i][j], 0, 0, 0);
                    accG[i][j] = __builtin_amdgcn_mfma_f32_16x16x32_bf16(a[i], bg[j], accG[i][j], 0, 0, 0);
                }
        }
    }
    #pragma unroll
    for (int i = 0; i < 4; ++i) {
        const int rbase = m0 + wm * 64 + i * 16 + (lane >> 4) * 4;
        #pragma unroll
        for (int j = 0; j < 2; ++j) {
            const int col = k * 192 + n0 + wn * 32 + j * 16 + (lane & 15);
            #pragma unroll
            for (int r = 0; r < 4; ++r) {
                const float g = accG[i][j][r];
                Y[(size_t)(rbase + r) * (KK * 3 * HH) + col] = f2bf(accV[i][j][r] * (g * sigm(g)));
            }
        }
    }
}

// ---------------- fused feature + scan: per (b,k,chunk32), 64 lanes = 64 heads ----------------
__launch_bounds__(64)
__global__ void feat_scan(const ushort_t* __restrict__ Zb, const float* __restrict__ conv_w,
                          const float* __restrict__ wk, const float* __restrict__ theta_raw,
                          const float* __restrict__ dt_scale, const float* __restrict__ dt_bias,
                          const float* __restrict__ log_A, const float* __restrict__ phase_scale,
                          float2* __restrict__ acc, float* __restrict__ pcum,
                          float2* __restrict__ cend, float* __restrict__ cp) {
    const int blk = blockIdx.x;                  // (b*KK+k)*NCHUNK + chunk
    const int bk = blk / NCHUNK, chunk = blk - bk * NCHUNK;
    const int b = bk / KK, k = bk - b * KK;
    const int h = threadIdx.x;
    const int t0 = chunk * LCHUNK;
    const int cm_ch = k * HH + h;
    const int cs_ch = DIM_MEM + k;

    const float w0 = conv_w[0 * DIM_CONV + cm_ch];
    const float w1 = conv_w[1 * DIM_CONV + cm_ch];
    const float w2 = conv_w[2 * DIM_CONV + cm_ch];
    const float w3 = conv_w[3 * DIM_CONV + cm_ch];
    const float s0 = conv_w[0 * DIM_CONV + cs_ch];
    const float s1 = conv_w[1 * DIM_CONV + cs_ch];
    const float s2 = conv_w[2 * DIM_CONV + cs_ch];
    const float s3 = conv_w[3 * DIM_CONV + cs_ch];
    const float wkh = wk[h];
    const float th = 0.001f + (3.0f - 0.001f) * sigm(theta_raw[cm_ch]);
    const float ps = phase_scale[k];
    const float dts = dt_scale[k], dtb = dt_bias[k];
    const float eA = expf(log_A[k]);

    const size_t rowb = (size_t)b * LL;
    auto zm_at = [&](int t) -> float {
        return (t >= 0) ? bf2f(Zb[(rowb + t) * DIM_TOTAL + cm_ch]) : 0.f;
    };
    auto zs_at = [&](int t) -> float {
        return (t >= 0) ? bf2f(Zb[(rowb + t) * DIM_TOTAL + cs_ch]) : 0.f;
    };
    float zm3 = zm_at(t0 - 3), zm2 = zm_at(t0 - 2), zm1 = zm_at(t0 - 1);
    float zs3 = zs_at(t0 - 3), zs2 = zs_at(t0 - 2), zs1 = zs_at(t0 - 1);

    float are = 0.f, aim = 0.f, P = 1.f;
    for (int tt = 0; tt < LCHUNK; ++tt) {
        const int t = t0 + tt;
        const float zm0 = bf2f(Zb[(rowb + t) * DIM_TOTAL + cm_ch]);
        const float zs0 = bf2f(Zb[(rowb + t) * DIM_TOTAL + cs_ch]);
        float cm = fmaf(w0, zm3, fmaf(w1, zm2, fmaf(w2, zm1, w3 * zm0)));
        float cs = fmaf(s0, zs3, fmaf(s1, zs2, fmaf(s2, zs1, s3 * zs0)));
        const float um = cm * sigm(cm);
        const float us = cs * sigm(cs);
        float ssq = um * um;
        #pragma unroll
        for (int off = 32; off > 0; off >>= 1) ssq += __shfl_xor(ssq, off);
        const float kval = um * rsqrtf(ssq * (1.0f / (float)HH) + 1e-6f) * wkh;
        float lin = fminf(fmaxf(fmaf(dts, us, dtb), -20.f), 20.f);
        float dt = fminf(fmaxf(softplusf(lin), 0.001f), 0.1f);
        const float Ad = fminf(fmaxf(-eA * dt, -20.f), 0.f);
        const float dec = expf(Ad);
        const float ks = kval * ps;
        const float phi = ks / (1.0f + fabsf(ks)) * th;
        const float kvw = kval * dt;
        float sp, cq;
        sincosf(phi, &sp, &cq);
        are = fmaf(dec, are, kvw * cq);
        aim = fmaf(dec, aim, kvw * sp);
        P *= dec;
        acc[((size_t)bk * LL + t) * HH + h] = make_float2(are, aim);
        if (h == 0) pcum[(size_t)bk * LL + t] = P;
        zm3 = zm2; zm2 = zm1; zm1 = zm0;
        zs3 = zs2; zs2 = zs1; zs1 = zs0;
    }
    cend[(size_t)blk * HH + h] = make_float2(are, aim);
    if (h == 0) cp[blk] = P;
}

// ---------------- scan phase B ----------------
__launch_bounds__(128)
__global__ void scan_b(const float* __restrict__ cend, const float* __restrict__ cp,
                       float* __restrict__ carry) {
    const int bk = blockIdx.x;
    const int c = threadIdx.x;
    float cur = 0.f;
    for (int ch = 0; ch < NCHUNK; ++ch) {
        const size_t idx = (size_t)bk * NCHUNK + ch;
        carry[idx * 128 + c] = cur;
        cur = fmaf(cp[idx], cur, cend[idx * 128 + c]);
    }
}

// ---------------- combine ----------------
__launch_bounds__(256)
__global__ void combine_kernel(const float2* __restrict__ acc, const float* __restrict__ pcum,
                               const float2* __restrict__ carry, const ushort_t* __restrict__ Zb,
                               const float* __restrict__ conv_w, const float* __restrict__ wq,
                               const float* __restrict__ w_int_raw, const float* __restrict__ W_gate,
                               const float* __restrict__ gn_weight,
                               ushort_t* __restrict__ ocnB, ushort_t* __restrict__ cskB) {
    __shared__ float q_sh[DIM_Q];
    __shared__ float g_sh[KK * 2 * HH];
    __shared__ float gl[KK];
    __shared__ float red[8];
    const int tok = blockIdx.x;
    const int b = tok / LL, t = tok % LL;
    const int tid = threadIdx.x;
    const int chunk = t / LCHUNK;
    const size_t zrow = (size_t)tok * DIM_TOTAL;

    if (tid < KK) gl[tid] = bf2f(Zb[zrow + DIM_CONV + DIM_SKIP + tid]);
    if (tid < DIM_SKIP) cskB[(size_t)tok * DIM_SKIP + tid] = Zb[zrow + DIM_CONV + tid];

    float part = 0.f;
    float qv[3];
    #pragma unroll
    for (int it = 0; it < 3; ++it) {
        const int c = tid + it * 256;
        const int ch = DIM_MEMT + c;
        float s = 0.f;
        #pragma unroll
        for (int j = 0; j < KSZ; ++j) {
            const int tt2 = t + j - (KSZ - 1);
            if (tt2 >= 0)
                s = fmaf(conv_w[j * DIM_CONV + ch],
                         bf2f(Zb[((size_t)(b * LL + tt2)) * DIM_TOTAL + ch]), s);
        }
        const float u = s * sigm(s);
        qv[it] = u;
        part = fmaf(u, u, part);
    }
    const float qss = blockReduceSum256(part, red);
    const float qrs = rsqrtf(qss / (float)DIM_Q + 1e-6f);
    #pragma unroll
    for (int it = 0; it < 3; ++it) {
        const int c = tid + it * 256;
        q_sh[c] = qv[it] * qrs * wq[c];
    }
    __syncthreads();

    float part2 = 0.f;
    #pragma unroll
    for (int it = 0; it < 3; ++it) {
        const int p = tid + it * 256;
        const int k = p >> 6, h = p & 63;
        const int kq = k >> 1;
        const size_t bkL = (size_t)(b * KK + k) * LL + t;
        const float pc = pcum[bkL];
        const float2 a2 = acc[bkL * HH + h];
        const float2 c2 = carry[((size_t)(b * KK + k) * NCHUNK + chunk) * HH + h];
        const float re = fmaf(pc, c2.x, a2.x);
        const float im = fmaf(pc, c2.y, a2.y);
        const float qre = q_sh[kq * 128 + 2 * h];
        const float qim = q_sh[kq * 128 + 2 * h + 1];
        float wr = w_int_raw[k * HH + h];
        wr = fminf(fmaxf(wr, -5.f), 5.f);
        const float wint = expf(wr);
        const float ore = (re * qre + im * qim) * wint;
        const float oim = (im * qre - re * qim) * wint;
        float gr = 0.f, gi = 0.f;
        const int cre = k * 128 + h, cim = k * 128 + 64 + h;
        #pragma unroll
        for (int i = 0; i < KK; ++i) {
            gr = fmaf(gl[i], W_gate[i * (KK * 2 * HH) + cre], gr);
            gi = fmaf(gl[i], W_gate[i * (KK * 2 * HH) + cim], gi);
        }
        const float g_re = ore * sigm(gr);
        const float g_im = oim * sigm(gi);
        g_sh[cre] = g_re;
        g_sh[cim] = g_im;
        part2 = fmaf(g_re, g_re, part2);
        part2 = fmaf(g_im, g_im, part2);
    }
    const float ss = blockReduceSum256(part2, red);
    const float rs = rsqrtf(ss / (float)(KK * 2 * HH) + 1e-6f);
    __syncthreads();
    #pragma unroll
    for (int it = 0; it < 6; ++it) {
        const int c = tid + it * 256;
        ocnB[(size_t)tok * (KK * 2 * HH) + c] = f2bf(g_sh[c] * rs * gn_weight[c]);
    }
}

// ---------------- launch ----------------
static inline size_t pass_need_bytes(int TP) {
    const size_t BP = (size_t)TP / LL;
    size_t total = 0;
    total += (size_t)TP * DIM_TOTAL * 2;            // Zb bf16
    total += (size_t)TP * KK * HH * 8;              // acc f32x2 (aliases WinT, then Y)
    total += (size_t)TP * KK * 4;                   // pcum
    total += BP * KK * NCHUNK * HH * 8;             // cend
    total += BP * KK * NCHUNK * 4;                  // cp
    total += BP * KK * NCHUNK * HH * 8;             // carry
    total += (size_t)TP * (KK * 2 * HH + DIM_SKIP) * 2; // ocnB + cskB (aliases xb)
    total += 8ull * 1024 * 1024;                    // WoutT + Btv + Btg
    return total;
}

extern "C" void kernel_launch(void* const* d_in, const int* in_sizes, int n_in,
                              void* d_out, int out_size, void* d_ws, size_t ws_size,
                              hipStream_t stream) {
    const float* x           = (const float*)d_in[0];
    const float* W_in        = (const float*)d_in[1];
    const float* conv_w      = (const float*)d_in[2];
    const float* wk          = (const float*)d_in[3];
    const float* wq          = (const float*)d_in[4];
    const float* theta_raw   = (const float*)d_in[5];
    const float* w_int_raw   = (const float*)d_in[6];
    const float* dt_scale    = (const float*)d_in[7];
    const float* dt_bias     = (const float*)d_in[8];
    const float* log_A       = (const float*)d_in[9];
    const float* phase_scale = (const float*)d_in[10];
    const float* W_gate      = (const float*)d_in[11];
    const float* gn_weight   = (const float*)d_in[12];
    const float* W_readout   = (const float*)d_in[13];
    const float* W_skip      = (const float*)d_in[14];
    const float* W_out       = (const float*)d_in[15];
    float* out = (float*)d_out;

    int passes = 4;
    if (ws_size >= pass_need_bytes(TTOK))        passes = 1;
    else if (ws_size >= pass_need_bytes(TTOK/2)) passes = 2;

    const int BP = BB / passes;
    const int TP = BP * LL;

    char* p = (char*)d_ws;
    ushort_t* Zb   = (ushort_t*)p;               p += (size_t)TP * DIM_TOTAL * 2;
    char* accR     = p;
    float2* acc    = (float2*)p;                 p += (size_t)TP * KK * HH * 8;
    float* pcum    = (float*)p;                  p += (size_t)TP * KK * 4;
    float2* cendv  = (float2*)p;                 p += (size_t)BP * KK * NCHUNK * HH * 8;
    float* cp      = (float*)p;                  p += (size_t)BP * KK * NCHUNK * 4;
    float2* carry  = (float2*)p;                 p += (size_t)BP * KK * NCHUNK * HH * 8;
    char* ocnR     = p;
    ushort_t* ocnB = (ushort_t*)p;               p += (size_t)TP * (KK * 2 * HH) * 2;
    ushort_t* cskB = (ushort_t*)p;               p += (size_t)TP * DIM_SKIP * 2;
    ushort_t* WoutT= (ushort_t*)p;               p += (size_t)768 * 2304 * 2;
    ushort_t* Btv  = (ushort_t*)p;               p += (size_t)KK * 192 * 320 * 2;
    ushort_t* Btg  = (ushort_t*)p;               p += (size_t)KK * 192 * 320 * 2;
    // aliases (stream-serial lifetime reuse):
    ushort_t* xb   = (ushort_t*)ocnR;   // [TP][768] bf16, dead after GEMM1
    ushort_t* WinT = (ushort_t*)accR;   // [1792][768] bf16, dead after GEMM1
    ushort_t* Y    = (ushort_t*)accR;   // [TP][2304] bf16 (<= acc bytes), written after combine

    for (int pass = 0; pass < passes; ++pass) {
        const float* xp = x   + (size_t)pass * TP * DD;
        float*       op = out + (size_t)pass * TP * DD;

        // input-only preps (front-loaded)
        cast_bf16<<<1024, 256, 0, stream>>>(xp, xb, TP * DD / 4);
        transpose_cast<<<dim3(N1PAD / 32, DD / 32), dim3(32, 8), 0, stream>>>(
            W_in, WinT, DD, N1REAL, N1PAD);
        transpose_cast<<<dim3(DD / 32, (KK * 3 * HH) / 32), dim3(32, 8), 0, stream>>>(
            W_out, WoutT, KK * 3 * HH, DD, DD);
        prep_bt<<<dim3(KK, 192), 320, 0, stream>>>(W_readout, W_skip, Btv, Btg);

        // 1. Zb = x @ W_in  (bf16 MFMA, bf16 output)
        mfma_gemm<true><<<dim3(TP / 128, N1PAD / 128), 256, 0, stream>>>(xb, WinT, Zb, N1REAL, DD);

        // 2. fused conv+feat+scan (mem path)
        feat_scan<<<BP * KK * NCHUNK, 64, 0, stream>>>(Zb, conv_w, wk, theta_raw, dt_scale,
                                                       dt_bias, log_A, phase_scale,
                                                       acc, pcum, cendv, cp);

        // 3. carry propagation
        scan_b<<<BP * KK, 128, 0, stream>>>((const float*)cendv, cp, (float*)carry);

        // 4. combine (inline q) -> ocn bf16 + cskip bf16
        combine_kernel<<<TP, 256, 0, stream>>>(acc, pcum, carry, Zb, conv_w, wq, w_int_raw,
                                               W_gate, gn_weight, ocnB, cskB);

        // 5. Y(bf16) = val*silu(gate) of grouped MFMA GEMM (readout + skip, K=320)
        gemm2_mfma<<<dim3(TP / 128, 3, KK), 256, 0, stream>>>(ocnB, cskB, Btv, Btg, Y);

        // 6. out = Y @ W_out  (bf16 MFMA, f32 output)
        mfma_gemm<false><<<dim3(TP / 128, DD / 128), 256, 0, stream>>>(Y, WoutT, op, DD, KK * 3 * HH);
    }
}